// Round 2
// baseline (50607.468 us; speedup 1.0000x reference)
//
#include <hip/hip_runtime.h>
#include <hip/hip_bf16.h>
#include <math.h>

#define BB 256
#define SS 256
#define DIN 300
#define D2 300
#define HH 512
#define D2P 320   // K=300 padded to multiple of 32

typedef __bf16 bf16x8 __attribute__((ext_vector_type(8)));
typedef float  f32x4  __attribute__((ext_vector_type(4)));

#define MFMA(a, b, c) __builtin_amdgcn_mfma_f32_16x16x32_bf16((a), (b), (c), 0, 0, 0)
// XOR-swizzle for LDS A-operand tiles (bf16 element index): kills the
// 16-way bank conflict of 1024/640-byte row strides on ds_read_b128.
#define SWZ(r, k) ((k) ^ (((r) & 7) << 3))

__device__ __forceinline__ float sigf(float x) { return 1.0f / (1.0f + expf(-x)); }

// Markidis-style fp32 -> bf16 hi/lo split. hi+lo reconstructs v to ~2^-17 rel.
__device__ __forceinline__ void bsplit(float v, __bf16* hi, __bf16* lo) {
    const __bf16 h = (__bf16)v;
    *hi = h;
    *lo = (__bf16)(v - (float)h);
}

// ---------------------------------------------------------------------------
// fp32 tiled GEMM — used ONLY for the big xp = tanh(x @ W_in + b_in)
// pre-pass (M=65536). mode 0 only.
// ---------------------------------------------------------------------------
__global__ __launch_bounds__(256) void gemm_tile(
    const float* __restrict__ A, int lda,
    const float* __restrict__ B, int ldb,
    int K, int N,
    float* __restrict__ C, int ldc,
    const float* __restrict__ aux, int auxStride, int mode)
{
    __shared__ float As[2][16][34];
    __shared__ float Bs[2][16][64];
    const int tid = threadIdx.x;
    const int m0 = blockIdx.y * 32;
    const int n0 = blockIdx.x * 64;
    const int tx = tid & 15;
    const int ty = tid >> 4;
    float acc[2][4] = {{0.f,0.f,0.f,0.f},{0.f,0.f,0.f,0.f}};
    const int NC = (K + 15) >> 4;

    float ra0, ra1, rb[4];
    auto load_regs = [&](int c) {
        const int k0 = c << 4;
        int e = tid, kk = e & 15, r = e >> 4;
        ra0 = (k0 + kk < K) ? A[(m0 + r) * lda + k0 + kk] : 0.f;
        e = tid + 256; kk = e & 15; r = e >> 4;
        ra1 = (k0 + kk < K) ? A[(m0 + r) * lda + k0 + kk] : 0.f;
#pragma unroll
        for (int i = 0; i < 4; ++i) {
            int e2 = tid + (i << 8);
            int kk2 = e2 >> 6, cc = e2 & 63;
            rb[i] = (k0 + kk2 < K && n0 + cc < N) ? B[(k0 + kk2) * ldb + n0 + cc] : 0.f;
        }
    };
    auto store_lds = [&](int buf) {
        int e = tid; As[buf][e & 15][e >> 4] = ra0;
        e = tid + 256; As[buf][e & 15][e >> 4] = ra1;
#pragma unroll
        for (int i = 0; i < 4; ++i) {
            int e2 = tid + (i << 8);
            Bs[buf][e2 >> 6][e2 & 63] = rb[i];
        }
    };

    load_regs(0); store_lds(0);
    for (int c = 0; c < NC; ++c) {
        __syncthreads();
        if (c + 1 < NC) load_regs(c + 1);
        const int buf = c & 1;
#pragma unroll
        for (int kk = 0; kk < 16; ++kk) {
            float2 a = *(const float2*)&As[buf][kk][ty * 2];
            float4 b = *(const float4*)&Bs[buf][kk][tx * 4];
            acc[0][0] += a.x * b.x; acc[0][1] += a.x * b.y;
            acc[0][2] += a.x * b.z; acc[0][3] += a.x * b.w;
            acc[1][0] += a.y * b.x; acc[1][1] += a.y * b.y;
            acc[1][2] += a.y * b.z; acc[1][3] += a.y * b.w;
        }
        if (c + 1 < NC) store_lds((c + 1) & 1);
    }

#pragma unroll
    for (int j = 0; j < 2; ++j) {
        const int r = m0 + ty * 2 + j;
#pragma unroll
        for (int i = 0; i < 4; ++i) {
            const int ccol = n0 + tx * 4 + i;
            if (ccol < N) {
                float v = acc[j][i];
                float outv;
                if (mode == 0) {
                    outv = tanhf(v + aux[ccol]);
                } else {
                    outv = 2.0f * sigf(v) * aux[(size_t)r * auxStride + ccol];
                }
                C[(size_t)r * ldc + ccol] = outv;
            }
        }
    }
}

// ---------------------------------------------------------------------------
// One-time weight prep: repack into MFMA-FRAGMENT-LINEAR order, hi/lo split.
// Logical layout [N][K] per matrix; element order: block bi = ntile*K32 + ks,
// then lane (64) x 8 elems with n = nt*16 + (lane&15), k = ks*32 + (lane>>4)*8 + e.
// A wave's B-fragment load is then ONE fully-coalesced 1 KB dwordx4 burst.
// ---------------------------------------------------------------------------
__global__ void split_weights(const float* __restrict__ Q, const float* __restrict__ R,
                              const float* __restrict__ Wih, const float* __restrict__ Whh,
                              __bf16* Qfh, __bf16* Qfl, __bf16* Rfh, __bf16* Rfl,
                              __bf16* Wfh, __bf16* Wfl, __bf16* Hfh, __bf16* Hfl)
{
    const int gid = blockIdx.x * blockDim.x + threadIdx.x;
    const int stride = gridDim.x * blockDim.x;
    // Q (512 x 300) -> [N=304][K=512]: 19 nt x 16 ks
    for (int i = gid; i < 19 * 16 * 512; i += stride) {
        const int bi = i >> 9, r = i & 511, lane = r >> 3, e = r & 7;
        const int nt = bi >> 4, ks = bi & 15;
        const int n = (nt << 4) + (lane & 15), k = (ks << 5) + ((lane >> 4) << 3) + e;
        const float v = (n < 300) ? Q[k * 300 + n] : 0.f;
        __bf16 hi, lo; bsplit(v, &hi, &lo); Qfh[i] = hi; Qfl[i] = lo;
    }
    // R (300 x 512) -> [N=512][K=320]: 32 nt x 10 ks
    for (int i = gid; i < 32 * 10 * 512; i += stride) {
        const int bi = i >> 9, r = i & 511, lane = r >> 3, e = r & 7;
        const int nt = bi / 10, ks = bi % 10;
        const int n = (nt << 4) + (lane & 15), k = (ks << 5) + ((lane >> 4) << 3) + e;
        const float v = (k < 300) ? R[k * 512 + n] : 0.f;
        __bf16 hi, lo; bsplit(v, &hi, &lo); Rfh[i] = hi; Rfl[i] = lo;
    }
    // Wih (300 x 2048) -> [N=2048][K=320]: 128 nt x 10 ks
    for (int i = gid; i < 128 * 10 * 512; i += stride) {
        const int bi = i >> 9, r = i & 511, lane = r >> 3, e = r & 7;
        const int nt = bi / 10, ks = bi % 10;
        const int n = (nt << 4) + (lane & 15), k = (ks << 5) + ((lane >> 4) << 3) + e;
        const float v = (k < 300) ? Wih[(size_t)k * 2048 + n] : 0.f;
        __bf16 hi, lo; bsplit(v, &hi, &lo); Wfh[i] = hi; Wfl[i] = lo;
    }
    // Whh (512 x 2048) -> [N=2048][K=512]: 128 nt x 16 ks
    for (int i = gid; i < 128 * 16 * 512; i += stride) {
        const int bi = i >> 9, r = i & 511, lane = r >> 3, e = r & 7;
        const int nt = bi >> 4, ks = bi & 15;
        const int n = (nt << 4) + (lane & 15), k = (ks << 5) + ((lane >> 4) << 3) + e;
        const float v = Whh[(size_t)k * 2048 + n];
        __bf16 hi, lo; bsplit(v, &hi, &lo); Hfh[i] = hi; Hfl[i] = lo;
    }
}

struct MogParams {
    const float* xp;
    const float* bih; const float* bhh;
    const __bf16 *Qfh, *Qfl, *Rfh, *Rfl, *Wfh, *Wfl, *Hfh, *Hfl;
    __hip_bfloat16* hseq;
};

// ---------------------------------------------------------------------------
// Persistent recurrence: 16 WGs x 512 threads, each WG owns 16 batch rows for
// the ENTIRE scan. All recurrent state (ht/xt2/ht2 hi+lo, ct) lives in LDS;
// zero inter-WG communication -> NO grid sync, NO fences, weights stay hot
// in L2/L3. Per phase the 8 waves split output n-tiles; each wave computes
// full-K accumulators (no cross-wave reduction) and applies the fused
// epilogue on its own MFMA D-fragment (col=lane&15, row=4*(lane>>4)+reg).
// ---------------------------------------------------------------------------
__global__ __launch_bounds__(512, 2) void mog_lstm(MogParams p)
{
    __shared__ __bf16 sHh[16][512], sHl[16][512];   // ht   hi/lo (A of phase A)
    __shared__ __bf16 sGh[16][512], sGl[16][512];   // ht2  hi/lo (A of phase C pt2)
    __shared__ __bf16 sXh[16][320], sXl[16][320];   // xt2  hi/lo (A of B, C pt1)
    __shared__ float  sC[16][516];                  // ct (pad 516: conflict-free)
    const int tid  = threadIdx.x;
    const int wid  = tid >> 6;              // 0..7
    const int lane = tid & 63;
    const int ln15 = lane & 15;
    const int kl   = (lane >> 4) << 3;      // k-offset of this lane's A-slice
    const int r0   = blockIdx.x << 4;       // 16 rows per WG
    const f32x4 vz = {0.f, 0.f, 0.f, 0.f};

    // zero-init recurrent state (incl. the swizzled K-pad region of sX)
    for (int i = tid; i < 16 * 512; i += 512) {
        sHh[i >> 9][i & 511] = (__bf16)0.f;
        sHl[i >> 9][i & 511] = (__bf16)0.f;
    }
    for (int i = tid; i < 16 * 320; i += 512) {
        sXh[i / 320][i % 320] = (__bf16)0.f;
        sXl[i / 320][i % 320] = (__bf16)0.f;
    }
    for (int i = tid; i < 16 * 516; i += 512) sC[i / 516][i % 516] = 0.f;

    // per-lane gate biases: wave's 4 h-tiles x 4 segments
    float bias[4][4];
#pragma unroll
    for (int i = 0; i < 4; ++i) {
        const int h = ((wid + (i << 3)) << 4) + ln15;
#pragma unroll
        for (int s = 0; s < 4; ++s) bias[i][s] = p.bih[s * 512 + h] + p.bhh[s * 512 + h];
    }
    __syncthreads();

    for (int t = 0; t < SS; ++t) {
        // ---- phase A: xt2 = 2*sig(ht @ Q) * xp[:,t,:]   (K=512, 19 n-tiles)
        for (int nt = wid; nt < 19; nt += 8) {
            f32x4 acc = vz, acc2 = vz;
            const __bf16* bh = p.Qfh + (((size_t)nt << 4) << 9) + (lane << 3);
            const __bf16* bl = p.Qfl + (((size_t)nt << 4) << 9) + (lane << 3);
#pragma unroll 4
            for (int ks = 0; ks < 16; ++ks) {
                const int ko = (ks << 5) + kl;
                bf16x8 ah = *(const bf16x8*)&sHh[ln15][SWZ(ln15, ko)];
                bf16x8 al = *(const bf16x8*)&sHl[ln15][SWZ(ln15, ko)];
                bf16x8 wh = *(const bf16x8*)(bh + ((size_t)ks << 9));
                bf16x8 wl = *(const bf16x8*)(bl + ((size_t)ks << 9));
                acc  = MFMA(ah, wh, acc);
                acc2 = MFMA(ah, wl, acc2);
                acc2 = MFMA(al, wh, acc2);
            }
            const int n = (nt << 4) + ln15;
#pragma unroll
            for (int j = 0; j < 4; ++j) {
                const int row = ((lane >> 4) << 2) + j;
                float v = 0.f;
                if (n < D2) {
                    const float s = acc[j] + acc2[j];
                    const float xpv = p.xp[((size_t)(r0 + row) * SS + t) * D2 + n];
                    v = 2.0f * sigf(s) * xpv;
                }
                __bf16 hi, lo; bsplit(v, &hi, &lo);
                sXh[row][SWZ(row, n)] = hi;
                sXl[row][SWZ(row, n)] = lo;
            }
        }
        __syncthreads();

        // ---- phase B: ht2 = 2*sig(xt2 @ R) * ht   (K=320, 32 n-tiles)
        for (int nt = wid; nt < 32; nt += 8) {
            f32x4 acc = vz, acc2 = vz;
            const __bf16* bh = p.Rfh + ((size_t)(nt * 10) << 9) + (lane << 3);
            const __bf16* bl = p.Rfl + ((size_t)(nt * 10) << 9) + (lane << 3);
#pragma unroll 5
            for (int ks = 0; ks < 10; ++ks) {
                const int ko = (ks << 5) + kl;
                bf16x8 ah = *(const bf16x8*)&sXh[ln15][SWZ(ln15, ko)];
                bf16x8 al = *(const bf16x8*)&sXl[ln15][SWZ(ln15, ko)];
                bf16x8 wh = *(const bf16x8*)(bh + ((size_t)ks << 9));
                bf16x8 wl = *(const bf16x8*)(bl + ((size_t)ks << 9));
                acc  = MFMA(ah, wh, acc);
                acc2 = MFMA(ah, wl, acc2);
                acc2 = MFMA(al, wh, acc2);
            }
            const int n = (nt << 4) + ln15;
#pragma unroll
            for (int j = 0; j < 4; ++j) {
                const int row = ((lane >> 4) << 2) + j;
                const float s = acc[j] + acc2[j];
                const int sn = SWZ(row, n);
                const float htf = (float)sHh[row][sn] + (float)sHl[row][sn];
                const float v = 2.0f * sigf(s) * htf;
                __bf16 hi, lo; bsplit(v, &hi, &lo);
                sGh[row][sn] = hi;
                sGl[row][sn] = lo;
            }
        }
        __syncthreads();

        // ---- phase C: gates = xt2@Wih + ht2@Whh + b; LSTM cell update.
        // Each wave: 4 h-tiles x 4 gate segments, full K (10 + 16 ksteps).
#pragma unroll
        for (int i = 0; i < 4; ++i) {
            const int ht0 = wid + (i << 3);
            f32x4 acc[4]  = {vz, vz, vz, vz};
            f32x4 acc2[4] = {vz, vz, vz, vz};
#pragma unroll 2
            for (int ks = 0; ks < 10; ++ks) {            // Wih part (A = xt2)
                const int ko = (ks << 5) + kl;
                bf16x8 ah = *(const bf16x8*)&sXh[ln15][SWZ(ln15, ko)];
                bf16x8 al = *(const bf16x8*)&sXl[ln15][SWZ(ln15, ko)];
#pragma unroll
                for (int s = 0; s < 4; ++s) {
                    const size_t off = ((size_t)(((s << 5) + ht0) * 10 + ks) << 9) + (lane << 3);
                    bf16x8 wh = *(const bf16x8*)(p.Wfh + off);
                    bf16x8 wl = *(const bf16x8*)(p.Wfl + off);
                    acc[s]  = MFMA(ah, wh, acc[s]);
                    acc2[s] = MFMA(ah, wl, acc2[s]);
                    acc2[s] = MFMA(al, wh, acc2[s]);
                }
            }
#pragma unroll 2
            for (int ks = 0; ks < 16; ++ks) {            // Whh part (A = ht2)
                const int ko = (ks << 5) + kl;
                bf16x8 ah = *(const bf16x8*)&sGh[ln15][SWZ(ln15, ko)];
                bf16x8 al = *(const bf16x8*)&sGl[ln15][SWZ(ln15, ko)];
#pragma unroll
                for (int s = 0; s < 4; ++s) {
                    const size_t off = ((size_t)((((s << 5) + ht0) << 4) + ks) << 9) + (lane << 3);
                    bf16x8 wh = *(const bf16x8*)(p.Hfh + off);
                    bf16x8 wl = *(const bf16x8*)(p.Hfl + off);
                    acc[s]  = MFMA(ah, wh, acc[s]);
                    acc2[s] = MFMA(ah, wl, acc2[s]);
                    acc2[s] = MFMA(al, wh, acc2[s]);
                }
            }
            const int h = (ht0 << 4) + ln15;
#pragma unroll
            for (int j = 0; j < 4; ++j) {
                const int row = ((lane >> 4) << 2) + j;
                const float g0 = acc[0][j] + acc2[0][j] + bias[i][0];
                const float g1 = acc[1][j] + acc2[1][j] + bias[i][1];
                const float g2 = acc[2][j] + acc2[2][j] + bias[i][2];
                const float g3 = acc[3][j] + acc2[3][j] + bias[i][3];
                const float cold = sC[row][h];
                const float cn = sigf(g1) * cold + sigf(g0) * tanhf(g2);
                const float hn = sigf(g3) * tanhf(cn);
                sC[row][h] = cn;
                __bf16 hi, lo; bsplit(hn, &hi, &lo);
                sHh[row][SWZ(row, h)] = hi;
                sHl[row][SWZ(row, h)] = lo;
                p.hseq[((size_t)(r0 + row) * SS + t) * HH + h] = __float2bfloat16(hn);
            }
        }
        __syncthreads();
    }
}

// ---------------------------------------------------------------------------
// Conv + relu + maxpool over time (unchanged; hseq is bf16 bit-identical).
// ---------------------------------------------------------------------------
__global__ __launch_bounds__(256) void conv_kernel(
    const __hip_bfloat16* __restrict__ hseq,
    const float* __restrict__ w3, const float* __restrict__ cb3,
    const float* __restrict__ w4, const float* __restrict__ cb4,
    const float* __restrict__ w5, const float* __restrict__ cb5,
    float* __restrict__ feats)
{
    __shared__ float sh[20 * 516];
    __shared__ float part[16 * 16 * 9];
    __shared__ int rmax[9];
    const int b = blockIdx.x;
    const int tid = threadIdx.x;
    if (tid < 9) rmax[tid] = 0;
    const int wv = tid >> 6, lane = tid & 63;
    const int t0l = lane >> 2, hs = lane & 3;

    for (int p = 0; p < 16; ++p) {
        __syncthreads();
#pragma unroll
        for (int i = 0; i < 5; ++i) {
            int e = tid + (i << 8);
            int row = e >> 6, q = e & 63;
            int tg = p * 16 + row;
            float v[8];
            if (tg < SS) {
                uint4 u = *(const uint4*)(hseq + (((size_t)b * SS + tg) << 9) + (q << 3));
                v[0] = __uint_as_float(u.x << 16); v[1] = __uint_as_float(u.x & 0xffff0000u);
                v[2] = __uint_as_float(u.y << 16); v[3] = __uint_as_float(u.y & 0xffff0000u);
                v[4] = __uint_as_float(u.z << 16); v[5] = __uint_as_float(u.z & 0xffff0000u);
                v[6] = __uint_as_float(u.w << 16); v[7] = __uint_as_float(u.w & 0xffff0000u);
            } else {
#pragma unroll
                for (int j = 0; j < 8; ++j) v[j] = 0.f;
            }
#pragma unroll
            for (int j = 0; j < 8; ++j) sh[row * 516 + q * 8 + j] = v[j];
        }
        __syncthreads();

        float acc[9];
#pragma unroll
        for (int j = 0; j < 9; ++j) acc[j] = 0.f;
        for (int k = 0; k < 32; ++k) {
            const int h = (wv << 7) + (k << 2) + hs;
            const float v0 = sh[(t0l + 0) * 516 + h];
            const float v1 = sh[(t0l + 1) * 516 + h];
            const float v2 = sh[(t0l + 2) * 516 + h];
            const float v3 = sh[(t0l + 3) * 516 + h];
            const float v4 = sh[(t0l + 4) * 516 + h];
#pragma unroll
            for (int f = 0; f < 3; ++f) {
                acc[f]     += v0 * w3[(f * 3 + 0) * 512 + h] + v1 * w3[(f * 3 + 1) * 512 + h]
                            + v2 * w3[(f * 3 + 2) * 512 + h];
                acc[3 + f] += v0 * w4[(f * 4 + 0) * 512 + h] + v1 * w4[(f * 4 + 1) * 512 + h]
                            + v2 * w4[(f * 4 + 2) * 512 + h] + v3 * w4[(f * 4 + 3) * 512 + h];
                acc[6 + f] += v0 * w5[(f * 5 + 0) * 512 + h] + v1 * w5[(f * 5 + 1) * 512 + h]
                            + v2 * w5[(f * 5 + 2) * 512 + h] + v3 * w5[(f * 5 + 3) * 512 + h]
                            + v4 * w5[(f * 5 + 4) * 512 + h];
            }
        }
        const int pi = (wv << 2) + hs;
#pragma unroll
        for (int j = 0; j < 9; ++j) part[(pi * 16 + t0l) * 9 + j] = acc[j];
        __syncthreads();
        if (tid < 144) {
            const int tl = tid / 9, j = tid % 9;
            float s = 0.f;
#pragma unroll
            for (int pp = 0; pp < 16; ++pp) s += part[(pp * 16 + tl) * 9 + j];
            const int fsz = j < 3 ? 3 : (j < 6 ? 4 : 5);
            const int t0 = p * 16 + tl;
            if (t0 <= SS - fsz) {
                const float bias = j < 3 ? cb3[j] : (j < 6 ? cb4[j - 3] : cb5[j - 6]);
                float v = s + bias;
                v = v > 0.f ? v : 0.f;
                atomicMax(&rmax[j], __float_as_int(v));
            }
        }
    }
    __syncthreads();
    if (tid < 9) feats[b * 9 + tid] = __int_as_float(rmax[tid]);
}

__global__ void final_kernel(const float* __restrict__ feats,
                             const float* __restrict__ lin_w,
                             const float* __restrict__ lin_b,
                             float* __restrict__ out)
{
    const int b = threadIdx.x;
    float o0 = lin_b[0], o1 = lin_b[1];
#pragma unroll
    for (int j = 0; j < 9; ++j) {
        const float f = feats[b * 9 + j];
        o0 += f * lin_w[j * 2 + 0];
        o1 += f * lin_w[j * 2 + 1];
    }
    out[b * 2 + 0] = o0;
    out[b * 2 + 1] = o1;
}

extern "C" void kernel_launch(void* const* d_in, const int* in_sizes, int n_in,
                              void* d_out, int out_size, void* d_ws, size_t ws_size,
                              hipStream_t stream) {
    const float* x    = (const float*)d_in[0];
    const float* W_in = (const float*)d_in[1];
    const float* b_in = (const float*)d_in[2];
    const float* Wih  = (const float*)d_in[3];
    const float* Whh  = (const float*)d_in[4];
    const float* bih  = (const float*)d_in[5];
    const float* bhh  = (const float*)d_in[6];
    const float* Q    = (const float*)d_in[7];
    const float* R    = (const float*)d_in[8];
    const float* lin_w = (const float*)d_in[9];
    const float* lin_b = (const float*)d_in[10];
    const float* w3 = (const float*)d_in[11];
    const float* cb3 = (const float*)d_in[12];
    const float* w4 = (const float*)d_in[13];
    const float* cb4 = (const float*)d_in[14];
    const float* w5 = (const float*)d_in[15];
    const float* cb5 = (const float*)d_in[16];

    char* base = (char*)d_ws;
    float*  xp    = (float*)base;                               // 65536 x 300 f32
    __hip_bfloat16* hseq = (__hip_bfloat16*)(xp + (size_t)BB * SS * D2);  // 256x256x512 bf16
    float*  feats = (float*)(hseq + (size_t)BB * SS * HH);      // 256 x 9
    __bf16* Qfh   = (__bf16*)(feats + BB * 9);                  // 19*16*512
    __bf16* Qfl   = Qfh + 19 * 16 * 512;
    __bf16* Rfh   = Qfl + 19 * 16 * 512;                        // 32*10*512
    __bf16* Rfl   = Rfh + 32 * 10 * 512;
    __bf16* Wfh   = Rfl + 32 * 10 * 512;                        // 128*10*512
    __bf16* Wfl   = Wfh + 128 * 10 * 512;
    __bf16* Hfh   = Wfl + 128 * 10 * 512;                       // 128*16*512
    __bf16* Hfl   = Hfh + (size_t)128 * 16 * 512;

    // xp = tanh(x @ W_in + b_in):  M=65536, K=300, N=300 (fp32)
    gemm_tile<<<dim3(5, 2048), 256, 0, stream>>>(x, DIN, W_in, D2, DIN, D2,
                                                 xp, D2, b_in, 0, 0);
    split_weights<<<dim3(1024), 256, 0, stream>>>(Q, R, Wih, Whh,
                                                  Qfh, Qfl, Rfh, Rfl,
                                                  Wfh, Wfl, Hfh, Hfl);

    MogParams P;
    P.xp = xp; P.bih = bih; P.bhh = bhh;
    P.Qfh = Qfh; P.Qfl = Qfl; P.Rfh = Rfh; P.Rfl = Rfl;
    P.Wfh = Wfh; P.Wfl = Wfl; P.Hfh = Hfh; P.Hfl = Hfl;
    P.hseq = hseq;
    mog_lstm<<<dim3(16), 512, 0, stream>>>(P);

    conv_kernel<<<dim3(256), 256, 0, stream>>>(hseq, w3, cb3, w4, cb4, w5, cb5, feats);
    final_kernel<<<dim3(1), 256, 0, stream>>>(feats, lin_w, lin_b, (float*)d_out);
}

// Round 3
// 34427.020 us; speedup vs baseline: 1.4700x; 1.4700x over previous
//
#include <hip/hip_runtime.h>
#include <hip/hip_bf16.h>
#include <math.h>

#define BB 256
#define SS 256
#define DIN 300
#define D2 300
#define HH 512
#define NWG 256
#define D2P 320   // K=300 padded to multiple of 32

typedef __bf16 bf16x8 __attribute__((ext_vector_type(8)));
typedef float  f32x4  __attribute__((ext_vector_type(4)));

#define MFMA(a, b, c) __builtin_amdgcn_mfma_f32_16x16x32_bf16((a), (b), (c), 0, 0, 0)

__device__ __forceinline__ float sigf(float x) { return 1.0f / (1.0f + expf(-x)); }

// Markidis-style fp32 -> bf16 hi/lo split. hi+lo reconstructs v to ~2^-17 rel.
__device__ __forceinline__ void bsplit(float v, __bf16* hi, __bf16* lo) {
    const __bf16 h = (__bf16)v;
    *hi = h;
    *lo = (__bf16)(v - (float)h);
}

// ---------------------------------------------------------------------------
// fp32 tiled GEMM — used ONLY for xp = tanh(x @ W_in + b_in) (M=65536).
// ---------------------------------------------------------------------------
__global__ __launch_bounds__(256) void gemm_tile(
    const float* __restrict__ A, int lda,
    const float* __restrict__ B, int ldb,
    int K, int N,
    float* __restrict__ C, int ldc,
    const float* __restrict__ aux, int auxStride, int mode)
{
    __shared__ float As[2][16][34];
    __shared__ float Bs[2][16][64];
    const int tid = threadIdx.x;
    const int m0 = blockIdx.y * 32;
    const int n0 = blockIdx.x * 64;
    const int tx = tid & 15;
    const int ty = tid >> 4;
    float acc[2][4] = {{0.f,0.f,0.f,0.f},{0.f,0.f,0.f,0.f}};
    const int NC = (K + 15) >> 4;

    float ra0, ra1, rb[4];
    auto load_regs = [&](int c) {
        const int k0 = c << 4;
        int e = tid, kk = e & 15, r = e >> 4;
        ra0 = (k0 + kk < K) ? A[(m0 + r) * lda + k0 + kk] : 0.f;
        e = tid + 256; kk = e & 15; r = e >> 4;
        ra1 = (k0 + kk < K) ? A[(m0 + r) * lda + k0 + kk] : 0.f;
#pragma unroll
        for (int i = 0; i < 4; ++i) {
            int e2 = tid + (i << 8);
            int kk2 = e2 >> 6, cc = e2 & 63;
            rb[i] = (k0 + kk2 < K && n0 + cc < N) ? B[(k0 + kk2) * ldb + n0 + cc] : 0.f;
        }
    };
    auto store_lds = [&](int buf) {
        int e = tid; As[buf][e & 15][e >> 4] = ra0;
        e = tid + 256; As[buf][e & 15][e >> 4] = ra1;
#pragma unroll
        for (int i = 0; i < 4; ++i) {
            int e2 = tid + (i << 8);
            Bs[buf][e2 >> 6][e2 & 63] = rb[i];
        }
    };

    load_regs(0); store_lds(0);
    for (int c = 0; c < NC; ++c) {
        __syncthreads();
        if (c + 1 < NC) load_regs(c + 1);
        const int buf = c & 1;
#pragma unroll
        for (int kk = 0; kk < 16; ++kk) {
            float2 a = *(const float2*)&As[buf][kk][ty * 2];
            float4 b = *(const float4*)&Bs[buf][kk][tx * 4];
            acc[0][0] += a.x * b.x; acc[0][1] += a.x * b.y;
            acc[0][2] += a.x * b.z; acc[0][3] += a.x * b.w;
            acc[1][0] += a.y * b.x; acc[1][1] += a.y * b.y;
            acc[1][2] += a.y * b.z; acc[1][3] += a.y * b.w;
        }
        if (c + 1 < NC) store_lds((c + 1) & 1);
    }

#pragma unroll
    for (int j = 0; j < 2; ++j) {
        const int r = m0 + ty * 2 + j;
#pragma unroll
        for (int i = 0; i < 4; ++i) {
            const int ccol = n0 + tx * 4 + i;
            if (ccol < N) {
                float v = acc[j][i];
                float outv;
                if (mode == 0) {
                    outv = tanhf(v + aux[ccol]);
                } else {
                    outv = 2.0f * sigf(v) * aux[(size_t)r * auxStride + ccol];
                }
                C[(size_t)r * ldc + ccol] = outv;
            }
        }
    }
}

// ---------------------------------------------------------------------------
// One-time weight prep: transpose to [n][k] (k contiguous for MFMA B-frags),
// zero-pad K to 320 / N to 304 where needed, split into hi/lo bf16.
// (verbatim from the round-1 kernel that passed)
// ---------------------------------------------------------------------------
__global__ void split_weights(const float* __restrict__ Q, const float* __restrict__ R,
                              const float* __restrict__ Wih, const float* __restrict__ Whh,
                              __bf16* Qth, __bf16* Qtl, __bf16* Rth, __bf16* Rtl,
                              __bf16* Wth, __bf16* Wtl, __bf16* Hth, __bf16* Htl)
{
    const int gid = blockIdx.x * blockDim.x + threadIdx.x;
    const int stride = gridDim.x * blockDim.x;
    // Q (512x300) -> Qt [304][512]
    for (int i = gid; i < 304 * 512; i += stride) {
        const int n = i >> 9, k = i & 511;
        const float v = (n < 300) ? Q[k * 300 + n] : 0.f;
        __bf16 hi, lo; bsplit(v, &hi, &lo); Qth[i] = hi; Qtl[i] = lo;
    }
    // R (300x512) -> Rt [512][320]
    for (int i = gid; i < 512 * D2P; i += stride) {
        const int n = i / D2P, k = i % D2P;
        const float v = (k < 300) ? R[k * 512 + n] : 0.f;
        __bf16 hi, lo; bsplit(v, &hi, &lo); Rth[i] = hi; Rtl[i] = lo;
    }
    // Wih (300x2048) -> Wt [2048][320]
    for (int i = gid; i < 2048 * D2P; i += stride) {
        const int n = i / D2P, k = i % D2P;
        const float v = (k < 300) ? Wih[(size_t)k * 2048 + n] : 0.f;
        __bf16 hi, lo; bsplit(v, &hi, &lo); Wth[i] = hi; Wtl[i] = lo;
    }
    // Whh (512x2048) -> Ht [2048][512]
    for (int i = gid; i < 2048 * 512; i += stride) {
        const int n = i >> 9, k = i & 511;
        const float v = Whh[(size_t)k * 2048 + n];
        __bf16 hi, lo; bsplit(v, &hi, &lo); Hth[i] = hi; Htl[i] = lo;
    }
}

// ---------------------------------------------------------------------------
// Hierarchical grid barrier. Arrivals: 8 group counters (group = bid&7 ->
// same-XCD under the %8 round-robin mapping, so those RMWs are local-L2-fast;
// correctness does NOT depend on the mapping). Group-lasts arrive on one
// global counter; final WG bumps the monotone generation word (release).
// Spinners poll RELAXED + s_sleep, then everyone takes one acquire fence.
// Release side: __threadfence() by all threads (as in the passing round-1).
// ---------------------------------------------------------------------------
__device__ __forceinline__ void grid_sync(unsigned* bar, unsigned target) {
    __threadfence();
    __syncthreads();
    if (threadIdx.x == 0) {
        unsigned* gc = bar + (blockIdx.x & 7) * 64;   // 256 B apart
        unsigned* gl = bar + 8 * 64;
        unsigned* gg = bar + 9 * 64;
        bool done = false;
        const unsigned a = __hip_atomic_fetch_add(gc, 1u, __ATOMIC_ACQ_REL, __HIP_MEMORY_SCOPE_AGENT);
        if (a == 31u) {
            __hip_atomic_store(gc, 0u, __ATOMIC_RELAXED, __HIP_MEMORY_SCOPE_AGENT);
            const unsigned b = __hip_atomic_fetch_add(gl, 1u, __ATOMIC_ACQ_REL, __HIP_MEMORY_SCOPE_AGENT);
            if (b == 7u) {
                __hip_atomic_store(gl, 0u, __ATOMIC_RELAXED, __HIP_MEMORY_SCOPE_AGENT);
                __hip_atomic_fetch_add(gg, 1u, __ATOMIC_ACQ_REL, __HIP_MEMORY_SCOPE_AGENT);
                done = true;
            }
        }
        if (!done) {
            while (__hip_atomic_load(gg, __ATOMIC_RELAXED, __HIP_MEMORY_SCOPE_AGENT) < target)
                __builtin_amdgcn_s_sleep(2);
        }
    }
    __syncthreads();
    __builtin_amdgcn_fence(__ATOMIC_ACQUIRE, "agent");   // invalidate L1/L2 before reads
}

struct MogParams {
    const float* xp;
    const float* bih; const float* bhh;
    const __bf16 *Qth, *Qtl, *Rth, *Rtl, *Wth, *Wtl, *Hth, *Htl;
    __bf16 *xt2h, *xt2l, *hth, *htl, *ht2h, *ht2l;
    float *ht, *ct;
    __hip_bfloat16* hseq;
    unsigned* bar;
};

// ---------------------------------------------------------------------------
// Persistent recurrence: 256 WGs x 256 threads (1/CU), whole t-loop inside,
// 3 hierarchical barriers per step. Tile ownership is XCD-sharded: virtual
// XCD v = bid&7 owns a fixed 1/8 of the weight columns in every phase (~1 MB),
// so post-fence refills come from L3 at ~1 MB/XCD/phase and ct/ht tiles stay
// WG-local across steps. Phase bodies (K-split over 4 waves + LDS reduce +
// fused epilogues) are verbatim from the round-1 kernel that passed.
// ---------------------------------------------------------------------------
__global__ __launch_bounds__(256, 1) void mog_lstm(MogParams p)
{
    __shared__ float red[4][4][256];   // [seg][wave][lane*4+j]
    const int tid  = threadIdx.x;
    const int wid  = tid >> 6;
    const int lane = tid & 63;
    const int ln15 = lane & 15;
    const int kl   = (lane >> 4) << 3;
    const int v    = blockIdx.x & 7;   // virtual XCD
    const int li   = blockIdx.x >> 3;  // 0..31 within group
    const f32x4 vz = {0.f, 0.f, 0.f, 0.f};
    unsigned bgen = 0;

    // phase-A n-tile share: 19 tiles over 8 groups (3,3,3,2,2,2,2,2)
    const int antc = (v < 3) ? 3 : 2;
    const int ant0 = (v < 3) ? v * 3 : 9 + (v - 3) * 2;

    for (int t = 0; t < SS; ++t) {
        // ---------- phase A: xt2 = 2*sig(ht @ Q) * xp[:,t,:]  (K=512)
        for (int i = li; i < antc * 16; i += 32) {
            const int nt = ant0 + (i >> 4);
            const int r0 = (i & 15) << 4;
            const int n0 = nt << 4;
            const __bf16* pah = p.hth + (r0 + ln15) * HH + kl;
            const __bf16* pal = p.htl + (r0 + ln15) * HH + kl;
            const __bf16* pbh = p.Qth + (n0 + ln15) * HH + kl;
            const __bf16* pbl = p.Qtl + (n0 + ln15) * HH + kl;
            f32x4 acc = vz, acc2 = vz;
#pragma unroll
            for (int s = 0; s < 4; ++s) {               // wave's 4 of 16 ksteps
                const int ko = (wid * 4 + s) * 32;
                bf16x8 ah = *(const bf16x8*)(pah + ko);
                bf16x8 al = *(const bf16x8*)(pal + ko);
                bf16x8 bh = *(const bf16x8*)(pbh + ko);
                bf16x8 bl = *(const bf16x8*)(pbl + ko);
                acc  = MFMA(ah, bh, acc);
                acc2 = MFMA(ah, bl, acc2);
                acc2 = MFMA(al, bh, acc2);
            }
            const f32x4 tot = acc + acc2;
#pragma unroll
            for (int j = 0; j < 4; ++j) red[0][wid][(lane << 2) + j] = tot[j];
            __syncthreads();
            {
                const int row = tid >> 4, col = tid & 15;
                const int l4 = ((((row >> 2) << 4) | col) << 2) | (row & 3);
                const float sm = red[0][0][l4] + red[0][1][l4] + red[0][2][l4] + red[0][3][l4];
                if (n0 + col < D2) {
                    const float xpv = p.xp[((size_t)(r0 + row) * SS + t) * D2 + (n0 + col)];
                    const float vv = 2.0f * sigf(sm) * xpv;
                    __bf16 hi, lo; bsplit(vv, &hi, &lo);
                    p.xt2h[(r0 + row) * D2P + n0 + col] = hi;
                    p.xt2l[(r0 + row) * D2P + n0 + col] = lo;
                }
            }
            __syncthreads();
        }
        grid_sync(p.bar, ++bgen);

        // ---------- phase B: ht2 = 2*sig(xt2 @ R) * ht   (K=320pad)
        {
            const int ksb = (wid < 2) ? wid * 3 : 2 + wid * 2;   // {0,3,6,8}
            const int kse = (wid < 2) ? ksb + 3 : ksb + 2;       // {3,6,8,10}
            for (int i = li; i < 64; i += 32) {
                const int nt = (v << 2) + (i >> 4);
                const int r0 = (i & 15) << 4;
                const int n0 = nt << 4;
                const __bf16* pah = p.xt2h + (r0 + ln15) * D2P + kl;
                const __bf16* pal = p.xt2l + (r0 + ln15) * D2P + kl;
                const __bf16* pbh = p.Rth + (n0 + ln15) * D2P + kl;
                const __bf16* pbl = p.Rtl + (n0 + ln15) * D2P + kl;
                f32x4 acc = vz, acc2 = vz;
#pragma unroll
                for (int ks = ksb; ks < kse; ++ks) {
                    const int ko = ks << 5;
                    bf16x8 ah = *(const bf16x8*)(pah + ko);
                    bf16x8 al = *(const bf16x8*)(pal + ko);
                    bf16x8 bh = *(const bf16x8*)(pbh + ko);
                    bf16x8 bl = *(const bf16x8*)(pbl + ko);
                    acc  = MFMA(ah, bh, acc);
                    acc2 = MFMA(ah, bl, acc2);
                    acc2 = MFMA(al, bh, acc2);
                }
                const f32x4 tot = acc + acc2;
#pragma unroll
                for (int j = 0; j < 4; ++j) red[0][wid][(lane << 2) + j] = tot[j];
                __syncthreads();
                {
                    const int row = tid >> 4, col = tid & 15;
                    const int l4 = ((((row >> 2) << 4) | col) << 2) | (row & 3);
                    const float sm = red[0][0][l4] + red[0][1][l4] + red[0][2][l4] + red[0][3][l4];
                    const size_t idx = (size_t)(r0 + row) * HH + (n0 + col);
                    const float vv = 2.0f * sigf(sm) * p.ht[idx];
                    __bf16 hi, lo; bsplit(vv, &hi, &lo);
                    p.ht2h[idx] = hi;
                    p.ht2l[idx] = lo;
                }
                __syncthreads();
            }
        }
        grid_sync(p.bar, ++bgen);

        // ---------- phase C: gates = xt2@Wih + ht2@Whh + b; LSTM cell update
        for (int i = li; i < 64; i += 32) {
            const int r0 = (i & 15) << 4;
            const int h0 = (((v << 2) + (i >> 4))) << 4;
            const __bf16 *pah, *pal, *pwh, *pwl;
            int sA, ksb, kse;
            if (wid < 2) {
                sA = D2P;
                pah = p.xt2h; pal = p.xt2l; pwh = p.Wth; pwl = p.Wtl;
                ksb = wid * 5; kse = ksb + 5;
            } else {
                sA = HH;
                pah = p.ht2h; pal = p.ht2l; pwh = p.Hth; pwl = p.Htl;
                ksb = (wid - 2) * 8; kse = ksb + 8;
            }
            const __bf16* Ah = pah + (r0 + ln15) * sA + kl;
            const __bf16* Al = pal + (r0 + ln15) * sA + kl;
            const __bf16* Bh = pwh + (h0 + ln15) * sA + kl;
            const __bf16* Bl = pwl + (h0 + ln15) * sA + kl;
            const int segoff = HH * sA;
            f32x4 acc[4]  = {vz, vz, vz, vz};
            f32x4 acc2[4] = {vz, vz, vz, vz};
#pragma unroll 2
            for (int ks = ksb; ks < kse; ++ks) {
                const int ko = ks << 5;
                bf16x8 ah = *(const bf16x8*)(Ah + ko);
                bf16x8 al = *(const bf16x8*)(Al + ko);
#pragma unroll
                for (int s = 0; s < 4; ++s) {
                    bf16x8 wh = *(const bf16x8*)(Bh + s * segoff + ko);
                    bf16x8 wl = *(const bf16x8*)(Bl + s * segoff + ko);
                    acc[s]  = MFMA(ah, wh, acc[s]);
                    acc2[s] = MFMA(ah, wl, acc2[s]);
                    acc2[s] = MFMA(al, wh, acc2[s]);
                }
            }
#pragma unroll
            for (int s = 0; s < 4; ++s) {
                const f32x4 tot = acc[s] + acc2[s];
#pragma unroll
                for (int j = 0; j < 4; ++j) red[s][wid][(lane << 2) + j] = tot[j];
            }
            __syncthreads();
            {
                const int row = tid >> 4, hl = tid & 15;
                const int l4 = ((((row >> 2) << 4) | hl) << 2) | (row & 3);
                const int h = h0 + hl;
                float g[4];
#pragma unroll
                for (int s = 0; s < 4; ++s) {
                    const int n = s * HH + h;
                    g[s] = red[s][0][l4] + red[s][1][l4] + red[s][2][l4] + red[s][3][l4]
                         + p.bih[n] + p.bhh[n];
                }
                const size_t idx = (size_t)(r0 + row) * HH + h;
                const float cold = p.ct[idx];
                const float cn = sigf(g[1]) * cold + sigf(g[0]) * tanhf(g[2]);
                const float hn = sigf(g[3]) * tanhf(cn);
                p.ct[idx] = cn;
                p.ht[idx] = hn;
                __bf16 hi, lo; bsplit(hn, &hi, &lo);
                p.hth[idx] = hi;
                p.htl[idx] = lo;
                p.hseq[((size_t)(r0 + row) * SS + t) * HH + h] = __float2bfloat16(hn);
            }
            __syncthreads();
        }
        grid_sync(p.bar, ++bgen);
    }
}

// ---------------------------------------------------------------------------
// Conv + relu + maxpool over time (unchanged; hseq is bf16 bit-identical).
// ---------------------------------------------------------------------------
__global__ __launch_bounds__(256) void conv_kernel(
    const __hip_bfloat16* __restrict__ hseq,
    const float* __restrict__ w3, const float* __restrict__ cb3,
    const float* __restrict__ w4, const float* __restrict__ cb4,
    const float* __restrict__ w5, const float* __restrict__ cb5,
    float* __restrict__ feats)
{
    __shared__ float sh[20 * 516];
    __shared__ float part[16 * 16 * 9];
    __shared__ int rmax[9];
    const int b = blockIdx.x;
    const int tid = threadIdx.x;
    if (tid < 9) rmax[tid] = 0;
    const int wv = tid >> 6, lane = tid & 63;
    const int t0l = lane >> 2, hs = lane & 3;

    for (int p = 0; p < 16; ++p) {
        __syncthreads();
#pragma unroll
        for (int i = 0; i < 5; ++i) {
            int e = tid + (i << 8);
            int row = e >> 6, q = e & 63;
            int tg = p * 16 + row;
            float v[8];
            if (tg < SS) {
                uint4 u = *(const uint4*)(hseq + (((size_t)b * SS + tg) << 9) + (q << 3));
                v[0] = __uint_as_float(u.x << 16); v[1] = __uint_as_float(u.x & 0xffff0000u);
                v[2] = __uint_as_float(u.y << 16); v[3] = __uint_as_float(u.y & 0xffff0000u);
                v[4] = __uint_as_float(u.z << 16); v[5] = __uint_as_float(u.z & 0xffff0000u);
                v[6] = __uint_as_float(u.w << 16); v[7] = __uint_as_float(u.w & 0xffff0000u);
            } else {
#pragma unroll
                for (int j = 0; j < 8; ++j) v[j] = 0.f;
            }
#pragma unroll
            for (int j = 0; j < 8; ++j) sh[row * 516 + q * 8 + j] = v[j];
        }
        __syncthreads();

        float acc[9];
#pragma unroll
        for (int j = 0; j < 9; ++j) acc[j] = 0.f;
        for (int k = 0; k < 32; ++k) {
            const int h = (wv << 7) + (k << 2) + hs;
            const float v0 = sh[(t0l + 0) * 516 + h];
            const float v1 = sh[(t0l + 1) * 516 + h];
            const float v2 = sh[(t0l + 2) * 516 + h];
            const float v3 = sh[(t0l + 3) * 516 + h];
            const float v4 = sh[(t0l + 4) * 516 + h];
#pragma unroll
            for (int f = 0; f < 3; ++f) {
                acc[f]     += v0 * w3[(f * 3 + 0) * 512 + h] + v1 * w3[(f * 3 + 1) * 512 + h]
                            + v2 * w3[(f * 3 + 2) * 512 + h];
                acc[3 + f] += v0 * w4[(f * 4 + 0) * 512 + h] + v1 * w4[(f * 4 + 1) * 512 + h]
                            + v2 * w4[(f * 4 + 2) * 512 + h] + v3 * w4[(f * 4 + 3) * 512 + h];
                acc[6 + f] += v0 * w5[(f * 5 + 0) * 512 + h] + v1 * w5[(f * 5 + 1) * 512 + h]
                            + v2 * w5[(f * 5 + 2) * 512 + h] + v3 * w5[(f * 5 + 3) * 512 + h]
                            + v4 * w5[(f * 5 + 4) * 512 + h];
            }
        }
        const int pi = (wv << 2) + hs;
#pragma unroll
        for (int j = 0; j < 9; ++j) part[(pi * 16 + t0l) * 9 + j] = acc[j];
        __syncthreads();
        if (tid < 144) {
            const int tl = tid / 9, j = tid % 9;
            float s = 0.f;
#pragma unroll
            for (int pp = 0; pp < 16; ++pp) s += part[(pp * 16 + tl) * 9 + j];
            const int fsz = j < 3 ? 3 : (j < 6 ? 4 : 5);
            const int t0 = p * 16 + tl;
            if (t0 <= SS - fsz) {
                const float bias = j < 3 ? cb3[j] : (j < 6 ? cb4[j - 3] : cb5[j - 6]);
                float v = s + bias;
                v = v > 0.f ? v : 0.f;
                atomicMax(&rmax[j], __float_as_int(v));
            }
        }
    }
    __syncthreads();
    if (tid < 9) feats[b * 9 + tid] = __int_as_float(rmax[tid]);
}

__global__ void final_kernel(const float* __restrict__ feats,
                             const float* __restrict__ lin_w,
                             const float* __restrict__ lin_b,
                             float* __restrict__ out)
{
    const int b = threadIdx.x;
    float o0 = lin_b[0], o1 = lin_b[1];
#pragma unroll
    for (int j = 0; j < 9; ++j) {
        const float f = feats[b * 9 + j];
        o0 += f * lin_w[j * 2 + 0];
        o1 += f * lin_w[j * 2 + 1];
    }
    out[b * 2 + 0] = o0;
    out[b * 2 + 1] = o1;
}

extern "C" void kernel_launch(void* const* d_in, const int* in_sizes, int n_in,
                              void* d_out, int out_size, void* d_ws, size_t ws_size,
                              hipStream_t stream) {
    const float* x    = (const float*)d_in[0];
    const float* W_in = (const float*)d_in[1];
    const float* b_in = (const float*)d_in[2];
    const float* Wih  = (const float*)d_in[3];
    const float* Whh  = (const float*)d_in[4];
    const float* bih  = (const float*)d_in[5];
    const float* bhh  = (const float*)d_in[6];
    const float* Q    = (const float*)d_in[7];
    const float* R    = (const float*)d_in[8];
    const float* lin_w = (const float*)d_in[9];
    const float* lin_b = (const float*)d_in[10];
    const float* w3 = (const float*)d_in[11];
    const float* cb3 = (const float*)d_in[12];
    const float* w4 = (const float*)d_in[13];
    const float* cb4 = (const float*)d_in[14];
    const float* w5 = (const float*)d_in[15];
    const float* cb5 = (const float*)d_in[16];

    char* base = (char*)d_ws;
    // --- zeroed region (barrier + recurrent state) ---
    unsigned* bar  = (unsigned*)base;                         // 4 KiB reserved
    float*  ht     = (float*)(base + 4096);                   // 256x512 f32
    float*  ct     = ht + (size_t)BB * HH;
    __bf16* hth    = (__bf16*)(ct + (size_t)BB * HH);         // 256x512 bf16
    __bf16* htl    = hth + (size_t)BB * HH;
    __bf16* ht2h   = htl + (size_t)BB * HH;
    __bf16* ht2l   = ht2h + (size_t)BB * HH;
    __bf16* xt2h   = ht2l + (size_t)BB * HH;                  // 256x320 bf16
    __bf16* xt2l   = xt2h + (size_t)BB * D2P;
    char*   zend   = (char*)(xt2l + (size_t)BB * D2P);
    const size_t zero_bytes = (size_t)(zend - base);          // ~2.4 MB
    // --- rest ---
    float*  xp     = (float*)zend;                            // 65536 x 300 f32
    __hip_bfloat16* hseq = (__hip_bfloat16*)(xp + (size_t)BB * SS * D2);
    float*  feats  = (float*)(hseq + (size_t)BB * SS * HH);
    __bf16* Qth    = (__bf16*)(feats + BB * 9);               // [304][512]
    __bf16* Qtl    = Qth + 304 * 512;
    __bf16* Rth    = Qtl + 304 * 512;                         // [512][320]
    __bf16* Rtl    = Rth + 512 * D2P;
    __bf16* Wth    = Rtl + 512 * D2P;                         // Wih^T [2048][320]
    __bf16* Wtl    = Wth + 2048 * D2P;
    __bf16* Hth    = Wtl + 2048 * D2P;                        // Whh^T [2048][512]
    __bf16* Htl    = Hth + (size_t)2048 * 512;

    hipMemsetAsync(base, 0, zero_bytes, stream);

    // xp = tanh(x @ W_in + b_in):  M=65536, K=300, N=300 (fp32)
    gemm_tile<<<dim3(5, 2048), 256, 0, stream>>>(x, DIN, W_in, D2, DIN, D2,
                                                 xp, D2, b_in, 0, 0);
    split_weights<<<dim3(1024), 256, 0, stream>>>(Q, R, Wih, Whh,
                                                  Qth, Qtl, Rth, Rtl,
                                                  Wth, Wtl, Hth, Htl);

    MogParams P;
    P.xp = xp; P.bih = bih; P.bhh = bhh;
    P.Qth = Qth; P.Qtl = Qtl; P.Rth = Rth; P.Rtl = Rtl;
    P.Wth = Wth; P.Wtl = Wtl; P.Hth = Hth; P.Htl = Htl;
    P.xt2h = xt2h; P.xt2l = xt2l; P.hth = hth; P.htl = htl;
    P.ht2h = ht2h; P.ht2l = ht2l;
    P.ht = ht; P.ct = ct; P.hseq = hseq; P.bar = bar;
    void* kargs[] = { &P };
    hipLaunchCooperativeKernel((const void*)mog_lstm, dim3(NWG), dim3(256),
                               kargs, 0, stream);

    conv_kernel<<<dim3(256), 256, 0, stream>>>(hseq, w3, cb3, w4, cb4, w5, cb5, feats);
    final_kernel<<<dim3(1), 256, 0, stream>>>(feats, lin_w, lin_b, (float*)d_out);
}

// Round 4
// 10830.140 us; speedup vs baseline: 4.6728x; 3.1788x over previous
//
#include <hip/hip_runtime.h>
#include <hip/hip_bf16.h>
#include <math.h>

#define BB 256
#define SS 256
#define DIN 300
#define D2 300
#define HH 512
#define NWG 256
#define D2P 320   // K=300 padded to multiple of 32

typedef __bf16 bf16x8 __attribute__((ext_vector_type(8)));
typedef float  f32x4  __attribute__((ext_vector_type(4)));
typedef unsigned int u32x4 __attribute__((ext_vector_type(4)));

#define MFMA(a, b, c) __builtin_amdgcn_mfma_f32_16x16x32_bf16((a), (b), (c), 0, 0, 0)

__device__ __forceinline__ float sigf(float x) { return 1.0f / (1.0f + expf(-x)); }

// Markidis-style fp32 -> bf16 hi/lo split. hi+lo reconstructs v to ~2^-17 rel.
__device__ __forceinline__ void bsplit(float v, __bf16* hi, __bf16* lo) {
    const __bf16 h = (__bf16)v;
    *hi = h;
    *lo = (__bf16)(v - (float)h);
}

// Device-coherent (L3) 16-byte load of a bf16x8 fragment: volatile -> sc0+sc1,
// bypasses L1/L2, reads the coherence point. Single global_load_dwordx4.
__device__ __forceinline__ bf16x8 vload16(const __bf16* p) {
    u32x4 u = *(const volatile u32x4*)p;
    union { u32x4 u; bf16x8 b; } c; c.u = u; return c.b;
}
// Device-coherent 2-byte store (write-through to L3).
__device__ __forceinline__ void vstore_bf16(__bf16* p, __bf16 v) {
    union { __bf16 b; unsigned short s; } c; c.b = v;
    *(volatile unsigned short*)p = c.s;
}

// ---------------------------------------------------------------------------
// fp32 tiled GEMM — used ONLY for xp = tanh(x @ W_in + b_in) (M=65536).
// ---------------------------------------------------------------------------
__global__ __launch_bounds__(256) void gemm_tile(
    const float* __restrict__ A, int lda,
    const float* __restrict__ B, int ldb,
    int K, int N,
    float* __restrict__ C, int ldc,
    const float* __restrict__ aux, int auxStride, int mode)
{
    __shared__ float As[2][16][34];
    __shared__ float Bs[2][16][64];
    const int tid = threadIdx.x;
    const int m0 = blockIdx.y * 32;
    const int n0 = blockIdx.x * 64;
    const int tx = tid & 15;
    const int ty = tid >> 4;
    float acc[2][4] = {{0.f,0.f,0.f,0.f},{0.f,0.f,0.f,0.f}};
    const int NC = (K + 15) >> 4;

    float ra0, ra1, rb[4];
    auto load_regs = [&](int c) {
        const int k0 = c << 4;
        int e = tid, kk = e & 15, r = e >> 4;
        ra0 = (k0 + kk < K) ? A[(m0 + r) * lda + k0 + kk] : 0.f;
        e = tid + 256; kk = e & 15; r = e >> 4;
        ra1 = (k0 + kk < K) ? A[(m0 + r) * lda + k0 + kk] : 0.f;
#pragma unroll
        for (int i = 0; i < 4; ++i) {
            int e2 = tid + (i << 8);
            int kk2 = e2 >> 6, cc = e2 & 63;
            rb[i] = (k0 + kk2 < K && n0 + cc < N) ? B[(k0 + kk2) * ldb + n0 + cc] : 0.f;
        }
    };
    auto store_lds = [&](int buf) {
        int e = tid; As[buf][e & 15][e >> 4] = ra0;
        e = tid + 256; As[buf][e & 15][e >> 4] = ra1;
#pragma unroll
        for (int i = 0; i < 4; ++i) {
            int e2 = tid + (i << 8);
            Bs[buf][e2 >> 6][e2 & 63] = rb[i];
        }
    };

    load_regs(0); store_lds(0);
    for (int c = 0; c < NC; ++c) {
        __syncthreads();
        if (c + 1 < NC) load_regs(c + 1);
        const int buf = c & 1;
#pragma unroll
        for (int kk = 0; kk < 16; ++kk) {
            float2 a = *(const float2*)&As[buf][kk][ty * 2];
            float4 b = *(const float4*)&Bs[buf][kk][tx * 4];
            acc[0][0] += a.x * b.x; acc[0][1] += a.x * b.y;
            acc[0][2] += a.x * b.z; acc[0][3] += a.x * b.w;
            acc[1][0] += a.y * b.x; acc[1][1] += a.y * b.y;
            acc[1][2] += a.y * b.z; acc[1][3] += a.y * b.w;
        }
        if (c + 1 < NC) store_lds((c + 1) & 1);
    }

#pragma unroll
    for (int j = 0; j < 2; ++j) {
        const int r = m0 + ty * 2 + j;
#pragma unroll
        for (int i = 0; i < 4; ++i) {
            const int ccol = n0 + tx * 4 + i;
            if (ccol < N) {
                float v = acc[j][i];
                float outv;
                if (mode == 0) {
                    outv = tanhf(v + aux[ccol]);
                } else {
                    outv = 2.0f * sigf(v) * aux[(size_t)r * auxStride + ccol];
                }
                C[(size_t)r * ldc + ccol] = outv;
            }
        }
    }
}

// ---------------------------------------------------------------------------
// One-time weight prep: transpose to [n][k], zero-pad, split into hi/lo bf16.
// ---------------------------------------------------------------------------
__global__ void split_weights(const float* __restrict__ Q, const float* __restrict__ R,
                              const float* __restrict__ Wih, const float* __restrict__ Whh,
                              __bf16* Qth, __bf16* Qtl, __bf16* Rth, __bf16* Rtl,
                              __bf16* Wth, __bf16* Wtl, __bf16* Hth, __bf16* Htl)
{
    const int gid = blockIdx.x * blockDim.x + threadIdx.x;
    const int stride = gridDim.x * blockDim.x;
    // Q (512x300) -> Qt [304][512]
    for (int i = gid; i < 304 * 512; i += stride) {
        const int n = i >> 9, k = i & 511;
        const float v = (n < 300) ? Q[k * 300 + n] : 0.f;
        __bf16 hi, lo; bsplit(v, &hi, &lo); Qth[i] = hi; Qtl[i] = lo;
    }
    // R (300x512) -> Rt [512][320]
    for (int i = gid; i < 512 * D2P; i += stride) {
        const int n = i / D2P, k = i % D2P;
        const float v = (k < 300) ? R[k * 512 + n] : 0.f;
        __bf16 hi, lo; bsplit(v, &hi, &lo); Rth[i] = hi; Rtl[i] = lo;
    }
    // Wih (300x2048) -> Wt [2048][320]
    for (int i = gid; i < 2048 * D2P; i += stride) {
        const int n = i / D2P, k = i % D2P;
        const float v = (k < 300) ? Wih[(size_t)k * 2048 + n] : 0.f;
        __bf16 hi, lo; bsplit(v, &hi, &lo); Wth[i] = hi; Wtl[i] = lo;
    }
    // Whh (512x2048) -> Ht [2048][512]
    for (int i = gid; i < 2048 * 512; i += stride) {
        const int n = i >> 9, k = i & 511;
        const float v = Whh[(size_t)k * 2048 + n];
        __bf16 hi, lo; bsplit(v, &hi, &lo); Hth[i] = hi; Htl[i] = lo;
    }
}

// ---------------------------------------------------------------------------
// SOFT grid barrier: NO cache maintenance anywhere. Monotone relaxed counters:
// 32 arrivals per group (bid&7) -> 8 group-lasts on a global counter -> last
// stores generation. Data visibility is handled entirely by the volatile
// (sc0+sc1, L3-coherent) accesses used for all cross-WG arrays, drained by
// s_waitcnt vmcnt(0) before arrival. Weights/xp/ht/ct keep normal cached
// access and are never invalidated.
// ---------------------------------------------------------------------------
__device__ __forceinline__ void soft_sync(unsigned* bar, unsigned gen) {
    asm volatile("s_waitcnt vmcnt(0)" ::: "memory");  // this wave's stores in L3
    __syncthreads();                                  // all waves drained + in WG sync
    if (threadIdx.x == 0) {
        unsigned* gc = bar + (blockIdx.x & 7) * 64;   // 256 B apart
        unsigned* gl = bar + 8 * 64;
        unsigned* gg = bar + 9 * 64;
        bool done = false;
        const unsigned a = __hip_atomic_fetch_add(gc, 1u, __ATOMIC_RELAXED, __HIP_MEMORY_SCOPE_AGENT);
        if (a == gen * 32u - 1u) {
            const unsigned b = __hip_atomic_fetch_add(gl, 1u, __ATOMIC_RELAXED, __HIP_MEMORY_SCOPE_AGENT);
            if (b == gen * 8u - 1u) {
                __hip_atomic_store(gg, gen, __ATOMIC_RELAXED, __HIP_MEMORY_SCOPE_AGENT);
                done = true;
            }
        }
        if (!done) {
            while (__hip_atomic_load(gg, __ATOMIC_RELAXED, __HIP_MEMORY_SCOPE_AGENT) < gen)
                __builtin_amdgcn_s_sleep(1);
        }
    }
    __syncthreads();
}

struct MogParams {
    const float* xp;
    const float* bih; const float* bhh;
    const __bf16 *Qth, *Qtl, *Rth, *Rtl, *Wth, *Wtl, *Hth, *Htl;
    __bf16 *xt2h, *xt2l, *hth, *htl, *ht2h, *ht2l;
    float *ht, *ct;
    __hip_bfloat16* hseq;
    unsigned* bar;
};

// ---------------------------------------------------------------------------
// Persistent recurrence: 256 WGs x 256 threads, 3 soft barriers per step.
// Ownership identical to round 3 (XCD-sharded columns; rows locked to li&15),
// which makes ht and ct WG-local (normal cached access). Cross-WG arrays
// (xt2 h/l, ht2 h/l, hth/htl) use volatile L3-coherent access only.
// ---------------------------------------------------------------------------
__global__ __launch_bounds__(256, 1) void mog_lstm(MogParams p)
{
    __shared__ float red[4][4][256];   // [seg][wave][lane*4+j]
    const int tid  = threadIdx.x;
    const int wid  = tid >> 6;
    const int lane = tid & 63;
    const int ln15 = lane & 15;
    const int kl   = (lane >> 4) << 3;
    const int v    = blockIdx.x & 7;   // virtual XCD
    const int li   = blockIdx.x >> 3;  // 0..31 within group
    const f32x4 vz = {0.f, 0.f, 0.f, 0.f};
    unsigned bgen = 0;

    // phase-A n-tile share: 19 tiles over 8 groups (3,3,3,2,2,2,2,2)
    const int antc = (v < 3) ? 3 : 2;
    const int ant0 = (v < 3) ? v * 3 : 9 + (v - 3) * 2;

    for (int t = 0; t < SS; ++t) {
        // ---------- phase A: xt2 = 2*sig(ht @ Q) * xp[:,t,:]  (K=512)
        for (int i = li; i < antc * 16; i += 32) {
            const int nt = ant0 + (i >> 4);
            const int r0 = (i & 15) << 4;
            const int n0 = nt << 4;
            const __bf16* pah = p.hth + (r0 + ln15) * HH + kl;
            const __bf16* pal = p.htl + (r0 + ln15) * HH + kl;
            const __bf16* pbh = p.Qth + (n0 + ln15) * HH + kl;
            const __bf16* pbl = p.Qtl + (n0 + ln15) * HH + kl;
            f32x4 acc = vz, acc2 = vz;
#pragma unroll
            for (int s = 0; s < 4; ++s) {               // wave's 4 of 16 ksteps
                const int ko = (wid * 4 + s) * 32;
                bf16x8 ah = vload16(pah + ko);
                bf16x8 al = vload16(pal + ko);
                bf16x8 bh = *(const bf16x8*)(pbh + ko);
                bf16x8 bl = *(const bf16x8*)(pbl + ko);
                acc  = MFMA(ah, bh, acc);
                acc2 = MFMA(ah, bl, acc2);
                acc2 = MFMA(al, bh, acc2);
            }
            const f32x4 tot = acc + acc2;
#pragma unroll
            for (int j = 0; j < 4; ++j) red[0][wid][(lane << 2) + j] = tot[j];
            __syncthreads();
            {
                const int row = tid >> 4, col = tid & 15;
                const int l4 = ((((row >> 2) << 4) | col) << 2) | (row & 3);
                const float sm = red[0][0][l4] + red[0][1][l4] + red[0][2][l4] + red[0][3][l4];
                if (n0 + col < D2) {
                    const float xpv = p.xp[((size_t)(r0 + row) * SS + t) * D2 + (n0 + col)];
                    const float vv = 2.0f * sigf(sm) * xpv;
                    __bf16 hi, lo; bsplit(vv, &hi, &lo);
                    vstore_bf16(&p.xt2h[(r0 + row) * D2P + n0 + col], hi);
                    vstore_bf16(&p.xt2l[(r0 + row) * D2P + n0 + col], lo);
                }
            }
            __syncthreads();
        }
        soft_sync(p.bar, ++bgen);

        // ---------- phase B: ht2 = 2*sig(xt2 @ R) * ht   (K=320pad)
        {
            const int ksb = (wid < 2) ? wid * 3 : 2 + wid * 2;   // {0,3,6,8}
            const int kse = (wid < 2) ? ksb + 3 : ksb + 2;       // {3,6,8,10}
            for (int i = li; i < 64; i += 32) {
                const int nt = (v << 2) + (i >> 4);
                const int r0 = (i & 15) << 4;
                const int n0 = nt << 4;
                const __bf16* pah = p.xt2h + (r0 + ln15) * D2P + kl;
                const __bf16* pal = p.xt2l + (r0 + ln15) * D2P + kl;
                const __bf16* pbh = p.Rth + (n0 + ln15) * D2P + kl;
                const __bf16* pbl = p.Rtl + (n0 + ln15) * D2P + kl;
                f32x4 acc = vz, acc2 = vz;
#pragma unroll
                for (int ks = ksb; ks < kse; ++ks) {
                    const int ko = ks << 5;
                    bf16x8 ah = vload16(pah + ko);
                    bf16x8 al = vload16(pal + ko);
                    bf16x8 bh = *(const bf16x8*)(pbh + ko);
                    bf16x8 bl = *(const bf16x8*)(pbl + ko);
                    acc  = MFMA(ah, bh, acc);
                    acc2 = MFMA(ah, bl, acc2);
                    acc2 = MFMA(al, bh, acc2);
                }
                const f32x4 tot = acc + acc2;
#pragma unroll
                for (int j = 0; j < 4; ++j) red[0][wid][(lane << 2) + j] = tot[j];
                __syncthreads();
                {
                    const int row = tid >> 4, col = tid & 15;
                    const int l4 = ((((row >> 2) << 4) | col) << 2) | (row & 3);
                    const float sm = red[0][0][l4] + red[0][1][l4] + red[0][2][l4] + red[0][3][l4];
                    const size_t idx = (size_t)(r0 + row) * HH + (n0 + col);
                    const float vv = 2.0f * sigf(sm) * p.ht[idx];   // ht is WG-local
                    __bf16 hi, lo; bsplit(vv, &hi, &lo);
                    vstore_bf16(&p.ht2h[idx], hi);
                    vstore_bf16(&p.ht2l[idx], lo);
                }
                __syncthreads();
            }
        }
        soft_sync(p.bar, ++bgen);

        // ---------- phase C: gates = xt2@Wih + ht2@Whh + b; LSTM cell update
        for (int i = li; i < 64; i += 32) {
            const int r0 = (i & 15) << 4;
            const int h0 = (((v << 2) + (i >> 4))) << 4;
            const __bf16 *pah, *pal, *pwh, *pwl;
            int sA, ksb, kse;
            if (wid < 2) {
                sA = D2P;
                pah = p.xt2h; pal = p.xt2l; pwh = p.Wth; pwl = p.Wtl;
                ksb = wid * 5; kse = ksb + 5;
            } else {
                sA = HH;
                pah = p.ht2h; pal = p.ht2l; pwh = p.Hth; pwl = p.Htl;
                ksb = (wid - 2) * 8; kse = ksb + 8;
            }
            const __bf16* Ah = pah + (r0 + ln15) * sA + kl;
            const __bf16* Al = pal + (r0 + ln15) * sA + kl;
            const __bf16* Bh = pwh + (h0 + ln15) * sA + kl;
            const __bf16* Bl = pwl + (h0 + ln15) * sA + kl;
            const int segoff = HH * sA;
            f32x4 acc[4]  = {vz, vz, vz, vz};
            f32x4 acc2[4] = {vz, vz, vz, vz};
#pragma unroll 2
            for (int ks = ksb; ks < kse; ++ks) {
                const int ko = ks << 5;
                bf16x8 ah = vload16(Ah + ko);
                bf16x8 al = vload16(Al + ko);
#pragma unroll
                for (int s = 0; s < 4; ++s) {
                    bf16x8 wh = *(const bf16x8*)(Bh + s * segoff + ko);
                    bf16x8 wl = *(const bf16x8*)(Bl + s * segoff + ko);
                    acc[s]  = MFMA(ah, wh, acc[s]);
                    acc2[s] = MFMA(ah, wl, acc2[s]);
                    acc2[s] = MFMA(al, wh, acc2[s]);
                }
            }
#pragma unroll
            for (int s = 0; s < 4; ++s) {
                const f32x4 tot = acc[s] + acc2[s];
#pragma unroll
                for (int j = 0; j < 4; ++j) red[s][wid][(lane << 2) + j] = tot[j];
            }
            __syncthreads();
            {
                const int row = tid >> 4, hl = tid & 15;
                const int l4 = ((((row >> 2) << 4) | hl) << 2) | (row & 3);
                const int h = h0 + hl;
                float g[4];
#pragma unroll
                for (int s = 0; s < 4; ++s) {
                    const int n = s * HH + h;
                    g[s] = red[s][0][l4] + red[s][1][l4] + red[s][2][l4] + red[s][3][l4]
                         + p.bih[n] + p.bhh[n];
                }
                const size_t idx = (size_t)(r0 + row) * HH + h;
                const float cold = p.ct[idx];                  // ct is WG-local
                const float cn = sigf(g[1]) * cold + sigf(g[0]) * tanhf(g[2]);
                const float hn = sigf(g[3]) * tanhf(cn);
                p.ct[idx] = cn;
                p.ht[idx] = hn;                                // ht is WG-local
                __bf16 hi, lo; bsplit(hn, &hi, &lo);
                vstore_bf16(&p.hth[idx], hi);
                vstore_bf16(&p.htl[idx], lo);
                p.hseq[((size_t)(r0 + row) * SS + t) * HH + h] = __float2bfloat16(hn);
            }
            __syncthreads();
        }
        soft_sync(p.bar, ++bgen);
    }
}

// ---------------------------------------------------------------------------
// Conv + relu + maxpool over time (unchanged; hseq is bf16 bit-identical).
// ---------------------------------------------------------------------------
__global__ __launch_bounds__(256) void conv_kernel(
    const __hip_bfloat16* __restrict__ hseq,
    const float* __restrict__ w3, const float* __restrict__ cb3,
    const float* __restrict__ w4, const float* __restrict__ cb4,
    const float* __restrict__ w5, const float* __restrict__ cb5,
    float* __restrict__ feats)
{
    __shared__ float sh[20 * 516];
    __shared__ float part[16 * 16 * 9];
    __shared__ int rmax[9];
    const int b = blockIdx.x;
    const int tid = threadIdx.x;
    if (tid < 9) rmax[tid] = 0;
    const int wv = tid >> 6, lane = tid & 63;
    const int t0l = lane >> 2, hs = lane & 3;

    for (int p = 0; p < 16; ++p) {
        __syncthreads();
#pragma unroll
        for (int i = 0; i < 5; ++i) {
            int e = tid + (i << 8);
            int row = e >> 6, q = e & 63;
            int tg = p * 16 + row;
            float v[8];
            if (tg < SS) {
                uint4 u = *(const uint4*)(hseq + (((size_t)b * SS + tg) << 9) + (q << 3));
                v[0] = __uint_as_float(u.x << 16); v[1] = __uint_as_float(u.x & 0xffff0000u);
                v[2] = __uint_as_float(u.y << 16); v[3] = __uint_as_float(u.y & 0xffff0000u);
                v[4] = __uint_as_float(u.z << 16); v[5] = __uint_as_float(u.z & 0xffff0000u);
                v[6] = __uint_as_float(u.w << 16); v[7] = __uint_as_float(u.w & 0xffff0000u);
            } else {
#pragma unroll
                for (int j = 0; j < 8; ++j) v[j] = 0.f;
            }
#pragma unroll
            for (int j = 0; j < 8; ++j) sh[row * 516 + q * 8 + j] = v[j];
        }
        __syncthreads();

        float acc[9];
#pragma unroll
        for (int j = 0; j < 9; ++j) acc[j] = 0.f;
        for (int k = 0; k < 32; ++k) {
            const int h = (wv << 7) + (k << 2) + hs;
            const float v0 = sh[(t0l + 0) * 516 + h];
            const float v1 = sh[(t0l + 1) * 516 + h];
            const float v2 = sh[(t0l + 2) * 516 + h];
            const float v3 = sh[(t0l + 3) * 516 + h];
            const float v4 = sh[(t0l + 4) * 516 + h];
#pragma unroll
            for (int f = 0; f < 3; ++f) {
                acc[f]     += v0 * w3[(f * 3 + 0) * 512 + h] + v1 * w3[(f * 3 + 1) * 512 + h]
                            + v2 * w3[(f * 3 + 2) * 512 + h];
                acc[3 + f] += v0 * w4[(f * 4 + 0) * 512 + h] + v1 * w4[(f * 4 + 1) * 512 + h]
                            + v2 * w4[(f * 4 + 2) * 512 + h] + v3 * w4[(f * 4 + 3) * 512 + h];
                acc[6 + f] += v0 * w5[(f * 5 + 0) * 512 + h] + v1 * w5[(f * 5 + 1) * 512 + h]
                            + v2 * w5[(f * 5 + 2) * 512 + h] + v3 * w5[(f * 5 + 3) * 512 + h]
                            + v4 * w5[(f * 5 + 4) * 512 + h];
            }
        }
        const int pi = (wv << 2) + hs;
#pragma unroll
        for (int j = 0; j < 9; ++j) part[(pi * 16 + t0l) * 9 + j] = acc[j];
        __syncthreads();
        if (tid < 144) {
            const int tl = tid / 9, j = tid % 9;
            float s = 0.f;
#pragma unroll
            for (int pp = 0; pp < 16; ++pp) s += part[(pp * 16 + tl) * 9 + j];
            const int fsz = j < 3 ? 3 : (j < 6 ? 4 : 5);
            const int t0 = p * 16 + tl;
            if (t0 <= SS - fsz) {
                const float bias = j < 3 ? cb3[j] : (j < 6 ? cb4[j - 3] : cb5[j - 6]);
                float v = s + bias;
                v = v > 0.f ? v : 0.f;
                atomicMax(&rmax[j], __float_as_int(v));
            }
        }
    }
    __syncthreads();
    if (tid < 9) feats[b * 9 + tid] = __int_as_float(rmax[tid]);
}

__global__ void final_kernel(const float* __restrict__ feats,
                             const float* __restrict__ lin_w,
                             const float* __restrict__ lin_b,
                             float* __restrict__ out)
{
    const int b = threadIdx.x;
    float o0 = lin_b[0], o1 = lin_b[1];
#pragma unroll
    for (int j = 0; j < 9; ++j) {
        const float f = feats[b * 9 + j];
        o0 += f * lin_w[j * 2 + 0];
        o1 += f * lin_w[j * 2 + 1];
    }
    out[b * 2 + 0] = o0;
    out[b * 2 + 1] = o1;
}

extern "C" void kernel_launch(void* const* d_in, const int* in_sizes, int n_in,
                              void* d_out, int out_size, void* d_ws, size_t ws_size,
                              hipStream_t stream) {
    const float* x    = (const float*)d_in[0];
    const float* W_in = (const float*)d_in[1];
    const float* b_in = (const float*)d_in[2];
    const float* Wih  = (const float*)d_in[3];
    const float* Whh  = (const float*)d_in[4];
    const float* bih  = (const float*)d_in[5];
    const float* bhh  = (const float*)d_in[6];
    const float* Q    = (const float*)d_in[7];
    const float* R    = (const float*)d_in[8];
    const float* lin_w = (const float*)d_in[9];
    const float* lin_b = (const float*)d_in[10];
    const float* w3 = (const float*)d_in[11];
    const float* cb3 = (const float*)d_in[12];
    const float* w4 = (const float*)d_in[13];
    const float* cb4 = (const float*)d_in[14];
    const float* w5 = (const float*)d_in[15];
    const float* cb5 = (const float*)d_in[16];

    char* base = (char*)d_ws;
    // --- zeroed region (barrier + recurrent state) ---
    unsigned* bar  = (unsigned*)base;                         // 4 KiB reserved
    float*  ht     = (float*)(base + 4096);                   // 256x512 f32
    float*  ct     = ht + (size_t)BB * HH;
    __bf16* hth    = (__bf16*)(ct + (size_t)BB * HH);         // 256x512 bf16
    __bf16* htl    = hth + (size_t)BB * HH;
    __bf16* ht2h   = htl + (size_t)BB * HH;
    __bf16* ht2l   = ht2h + (size_t)BB * HH;
    __bf16* xt2h   = ht2l + (size_t)BB * HH;                  // 256x320 bf16
    __bf16* xt2l   = xt2h + (size_t)BB * D2P;
    char*   zend   = (char*)(xt2l + (size_t)BB * D2P);
    const size_t zero_bytes = (size_t)(zend - base);          // ~2.4 MB
    // --- rest ---
    float*  xp     = (float*)zend;                            // 65536 x 300 f32
    __hip_bfloat16* hseq = (__hip_bfloat16*)(xp + (size_t)BB * SS * D2);
    float*  feats  = (float*)(hseq + (size_t)BB * SS * HH);
    __bf16* Qth    = (__bf16*)(feats + BB * 9);               // [304][512]
    __bf16* Qtl    = Qth + 304 * 512;
    __bf16* Rth    = Qtl + 304 * 512;                         // [512][320]
    __bf16* Rtl    = Rth + 512 * D2P;
    __bf16* Wth    = Rtl + 512 * D2P;                         // Wih^T [2048][320]
    __bf16* Wtl    = Wth + 2048 * D2P;
    __bf16* Hth    = Wtl + 2048 * D2P;                        // Whh^T [2048][512]
    __bf16* Htl    = Hth + (size_t)2048 * 512;

    hipMemsetAsync(base, 0, zero_bytes, stream);

    // xp = tanh(x @ W_in + b_in):  M=65536, K=300, N=300 (fp32)
    gemm_tile<<<dim3(5, 2048), 256, 0, stream>>>(x, DIN, W_in, D2, DIN, D2,
                                                 xp, D2, b_in, 0, 0);
    split_weights<<<dim3(1024), 256, 0, stream>>>(Q, R, Wih, Whh,
                                                  Qth, Qtl, Rth, Rtl,
                                                  Wth, Wtl, Hth, Htl);

    MogParams P;
    P.xp = xp; P.bih = bih; P.bhh = bhh;
    P.Qth = Qth; P.Qtl = Qtl; P.Rth = Rth; P.Rtl = Rtl;
    P.Wth = Wth; P.Wtl = Wtl; P.Hth = Hth; P.Htl = Htl;
    P.xt2h = xt2h; P.xt2l = xt2l; P.hth = hth; P.htl = htl;
    P.ht2h = ht2h; P.ht2l = ht2l;
    P.ht = ht; P.ct = ct; P.hseq = hseq; P.bar = bar;
    void* kargs[] = { &P };
    hipLaunchCooperativeKernel((const void*)mog_lstm, dim3(NWG), dim3(256),
                               kargs, 0, stream);

    conv_kernel<<<dim3(256), 256, 0, stream>>>(hseq, w3, cb3, w4, cb4, w5, cb5, feats);
    final_kernel<<<dim3(1), 256, 0, stream>>>(feats, lin_w, lin_b, (float*)d_out);
}

// Round 7
// 9627.153 us; speedup vs baseline: 5.2567x; 1.1250x over previous
//
#include <hip/hip_runtime.h>
#include <hip/hip_bf16.h>
#include <math.h>

#define BB 256
#define SS 256
#define DIN 300
#define D2 300
#define HH 512
#define NWG 256
#define D2P 320   // K=300 padded to multiple of 32

typedef __bf16 bf16x8 __attribute__((ext_vector_type(8)));
typedef float  f32x4  __attribute__((ext_vector_type(4)));
typedef unsigned int u32x4 __attribute__((ext_vector_type(4)));

#define MFMA(a, b, c) __builtin_amdgcn_mfma_f32_16x16x32_bf16((a), (b), (c), 0, 0, 0)

__device__ __forceinline__ float sigf(float x) { return 1.0f / (1.0f + expf(-x)); }

// Markidis-style fp32 -> bf16 hi/lo split. hi+lo reconstructs v to ~2^-17 rel.
__device__ __forceinline__ void bsplit(float v, __bf16* hi, __bf16* lo) {
    const __bf16 h = (__bf16)v;
    *hi = h;
    *lo = (__bf16)(v - (float)h);
}

// Device-coherent (L3) 16-byte load of a bf16x8 fragment: volatile -> sc0+sc1,
// bypasses L1/L2, reads the coherence point. Single global_load_dwordx4.
__device__ __forceinline__ bf16x8 vload16(const __bf16* p) {
    u32x4 u = *(const volatile u32x4*)p;
    union { u32x4 u; bf16x8 b; } c; c.u = u; return c.b;
}
// Device-coherent 2-byte store (write-through to L3).
__device__ __forceinline__ void vstore_bf16(__bf16* p, __bf16 v) {
    union { __bf16 b; unsigned short s; } c; c.b = v;
    *(volatile unsigned short*)p = c.s;
}

// ---------------------------------------------------------------------------
// fp32 tiled GEMM — used ONLY for xp = tanh(x @ W_in + b_in) (M=65536).
// ---------------------------------------------------------------------------
__global__ __launch_bounds__(256) void gemm_tile(
    const float* __restrict__ A, int lda,
    const float* __restrict__ B, int ldb,
    int K, int N,
    float* __restrict__ C, int ldc,
    const float* __restrict__ aux, int auxStride, int mode)
{
    __shared__ float As[2][16][34];
    __shared__ float Bs[2][16][64];
    const int tid = threadIdx.x;
    const int m0 = blockIdx.y * 32;
    const int n0 = blockIdx.x * 64;
    const int tx = tid & 15;
    const int ty = tid >> 4;
    float acc[2][4] = {{0.f,0.f,0.f,0.f},{0.f,0.f,0.f,0.f}};
    const int NC = (K + 15) >> 4;

    float ra0, ra1, rb[4];
    auto load_regs = [&](int c) {
        const int k0 = c << 4;
        int e = tid, kk = e & 15, r = e >> 4;
        ra0 = (k0 + kk < K) ? A[(m0 + r) * lda + k0 + kk] : 0.f;
        e = tid + 256; kk = e & 15; r = e >> 4;
        ra1 = (k0 + kk < K) ? A[(m0 + r) * lda + k0 + kk] : 0.f;
#pragma unroll
        for (int i = 0; i < 4; ++i) {
            int e2 = tid + (i << 8);
            int kk2 = e2 >> 6, cc = e2 & 63;
            rb[i] = (k0 + kk2 < K && n0 + cc < N) ? B[(k0 + kk2) * ldb + n0 + cc] : 0.f;
        }
    };
    auto store_lds = [&](int buf) {
        int e = tid; As[buf][e & 15][e >> 4] = ra0;
        e = tid + 256; As[buf][e & 15][e >> 4] = ra1;
#pragma unroll
        for (int i = 0; i < 4; ++i) {
            int e2 = tid + (i << 8);
            Bs[buf][e2 >> 6][e2 & 63] = rb[i];
        }
    };

    load_regs(0); store_lds(0);
    for (int c = 0; c < NC; ++c) {
        __syncthreads();
        if (c + 1 < NC) load_regs(c + 1);
        const int buf = c & 1;
#pragma unroll
        for (int kk = 0; kk < 16; ++kk) {
            float2 a = *(const float2*)&As[buf][kk][ty * 2];
            float4 b = *(const float4*)&Bs[buf][kk][tx * 4];
            acc[0][0] += a.x * b.x; acc[0][1] += a.x * b.y;
            acc[0][2] += a.x * b.z; acc[0][3] += a.x * b.w;
            acc[1][0] += a.y * b.x; acc[1][1] += a.y * b.y;
            acc[1][2] += a.y * b.z; acc[1][3] += a.y * b.w;
        }
        if (c + 1 < NC) store_lds((c + 1) & 1);
    }

#pragma unroll
    for (int j = 0; j < 2; ++j) {
        const int r = m0 + ty * 2 + j;
#pragma unroll
        for (int i = 0; i < 4; ++i) {
            const int ccol = n0 + tx * 4 + i;
            if (ccol < N) {
                float v = acc[j][i];
                float outv;
                if (mode == 0) {
                    outv = tanhf(v + aux[ccol]);
                } else {
                    outv = 2.0f * sigf(v) * aux[(size_t)r * auxStride + ccol];
                }
                C[(size_t)r * ldc + ccol] = outv;
            }
        }
    }
}

// ---------------------------------------------------------------------------
// One-time weight prep: transpose to [n][k], zero-pad, split into hi/lo bf16.
// ---------------------------------------------------------------------------
__global__ void split_weights(const float* __restrict__ Q, const float* __restrict__ R,
                              const float* __restrict__ Wih, const float* __restrict__ Whh,
                              __bf16* Qth, __bf16* Qtl, __bf16* Rth, __bf16* Rtl,
                              __bf16* Wth, __bf16* Wtl, __bf16* Hth, __bf16* Htl)
{
    const int gid = blockIdx.x * blockDim.x + threadIdx.x;
    const int stride = gridDim.x * blockDim.x;
    // Q (512x300) -> Qt [304][512]
    for (int i = gid; i < 304 * 512; i += stride) {
        const int n = i >> 9, k = i & 511;
        const float v = (n < 300) ? Q[k * 300 + n] : 0.f;
        __bf16 hi, lo; bsplit(v, &hi, &lo); Qth[i] = hi; Qtl[i] = lo;
    }
    // R (300x512) -> Rt [512][320]
    for (int i = gid; i < 512 * D2P; i += stride) {
        const int n = i / D2P, k = i % D2P;
        const float v = (k < 300) ? R[k * 512 + n] : 0.f;
        __bf16 hi, lo; bsplit(v, &hi, &lo); Rth[i] = hi; Rtl[i] = lo;
    }
    // Wih (300x2048) -> Wt [2048][320]
    for (int i = gid; i < 2048 * D2P; i += stride) {
        const int n = i / D2P, k = i % D2P;
        const float v = (k < 300) ? Wih[(size_t)k * 2048 + n] : 0.f;
        __bf16 hi, lo; bsplit(v, &hi, &lo); Wth[i] = hi; Wtl[i] = lo;
    }
    // Whh (512x2048) -> Ht [2048][512]
    for (int i = gid; i < 2048 * 512; i += stride) {
        const int n = i >> 9, k = i & 511;
        const float v = Whh[(size_t)k * 2048 + n];
        __bf16 hi, lo; bsplit(v, &hi, &lo); Hth[i] = hi; Htl[i] = lo;
    }
}

// ---------------------------------------------------------------------------
// SOFT grid barrier (no cache maintenance): relaxed monotone counters.
// 32 arrivals per group (bid&7) -> 8 group-lasts -> generation store.
// Visibility comes from the volatile L3-coherent accesses + vmcnt drain.
// (byte-identical to the round-4 kernel that passed)
// ---------------------------------------------------------------------------
__device__ __forceinline__ void soft_sync(unsigned* bar, unsigned gen) {
    asm volatile("s_waitcnt vmcnt(0)" ::: "memory");  // this wave's stores in L3
    __syncthreads();                                  // all waves drained + in WG sync
    if (threadIdx.x == 0) {
        unsigned* gc = bar + (blockIdx.x & 7) * 64;   // 256 B apart
        unsigned* gl = bar + 8 * 64;
        unsigned* gg = bar + 9 * 64;
        bool done = false;
        const unsigned a = __hip_atomic_fetch_add(gc, 1u, __ATOMIC_RELAXED, __HIP_MEMORY_SCOPE_AGENT);
        if (a == gen * 32u - 1u) {
            const unsigned b = __hip_atomic_fetch_add(gl, 1u, __ATOMIC_RELAXED, __HIP_MEMORY_SCOPE_AGENT);
            if (b == gen * 8u - 1u) {
                __hip_atomic_store(gg, gen, __ATOMIC_RELAXED, __HIP_MEMORY_SCOPE_AGENT);
                done = true;
            }
        }
        if (!done) {
            while (__hip_atomic_load(gg, __ATOMIC_RELAXED, __HIP_MEMORY_SCOPE_AGENT) < gen)
                __builtin_amdgcn_s_sleep(1);
        }
    }
    __syncthreads();
}

struct MogParams {
    const float* xp;
    const float* bih; const float* bhh;
    const __bf16 *Qth, *Qtl, *Rth, *Rtl, *Wth, *Wtl, *Hth, *Htl;
    __bf16 *xt2h, *xt2l, *hth, *htl, *ht2h, *ht2l;
    float *ht, *ct;
    __hip_bfloat16* hseq;
    unsigned* bar;
};

// ---------------------------------------------------------------------------
// Persistent recurrence: 256 WGs x 256 threads, 3 soft barriers per step.
// IDENTICAL structure to the round-4 passing kernel (4-wave K-split + LDS
// reduce + volatile cross-WG arrays + relaxed barrier). Single change:
// phases B and C now use 16x32 tiles (one tile per WG instead of two serial
// 16x16 tiles) — the two column-halves share the same A-fragments, so the
// per-step serial volatile-load chains, reduces and epilogues are halved.
// ---------------------------------------------------------------------------
__global__ __launch_bounds__(256, 1) void mog_lstm(MogParams p)
{
    __shared__ float red[8][4][256];   // [colhalf|seg*2+colhalf][wave][lane*4+j]
    const int tid  = threadIdx.x;
    const int wid  = tid >> 6;
    const int lane = tid & 63;
    const int ln15 = lane & 15;
    const int kl   = (lane >> 4) << 3;
    const int v    = blockIdx.x & 7;   // virtual XCD
    const int li   = blockIdx.x >> 3;  // 0..31 within group
    const f32x4 vz = {0.f, 0.f, 0.f, 0.f};
    unsigned bgen = 0;

    // phase-A n-tile share: 19 tiles over 8 groups (3,3,3,2,2,2,2,2)
    const int antc = (v < 3) ? 3 : 2;
    const int ant0 = (v < 3) ? v * 3 : 9 + (v - 3) * 2;

    // this WG's fixed 16x32 tile for phases B and C
    const int pair = (v << 1) + (li >> 4);   // 0..15 (pair of n/h-tiles)
    const int rbB  = (li & 15) << 4;         // row-block for B/C

    for (int t = 0; t < SS; ++t) {
        // ---------- phase A: xt2 = 2*sig(ht @ Q) * xp[:,t,:]  (K=512)
        for (int i = li; i < antc * 16; i += 32) {
            const int nt = ant0 + (i >> 4);
            const int r0 = (i & 15) << 4;
            const int n0 = nt << 4;
            const __bf16* pah = p.hth + (r0 + ln15) * HH + kl;
            const __bf16* pal = p.htl + (r0 + ln15) * HH + kl;
            const __bf16* pbh = p.Qth + (n0 + ln15) * HH + kl;
            const __bf16* pbl = p.Qtl + (n0 + ln15) * HH + kl;
            f32x4 acc = vz, acc2 = vz;
#pragma unroll
            for (int s = 0; s < 4; ++s) {               // wave's 4 of 16 ksteps
                const int ko = (wid * 4 + s) * 32;
                bf16x8 ah = vload16(pah + ko);
                bf16x8 al = vload16(pal + ko);
                bf16x8 bh = *(const bf16x8*)(pbh + ko);
                bf16x8 bl = *(const bf16x8*)(pbl + ko);
                acc  = MFMA(ah, bh, acc);
                acc2 = MFMA(ah, bl, acc2);
                acc2 = MFMA(al, bh, acc2);
            }
            const f32x4 tot = acc + acc2;
#pragma unroll
            for (int j = 0; j < 4; ++j) red[0][wid][(lane << 2) + j] = tot[j];
            __syncthreads();
            {
                const int row = tid >> 4, col = tid & 15;
                const int l4 = ((((row >> 2) << 4) | col) << 2) | (row & 3);
                const float sm = red[0][0][l4] + red[0][1][l4] + red[0][2][l4] + red[0][3][l4];
                if (n0 + col < D2) {
                    const float xpv = p.xp[((size_t)(r0 + row) * SS + t) * D2 + (n0 + col)];
                    const float vv = 2.0f * sigf(sm) * xpv;
                    __bf16 hi, lo; bsplit(vv, &hi, &lo);
                    vstore_bf16(&p.xt2h[(r0 + row) * D2P + n0 + col], hi);
                    vstore_bf16(&p.xt2l[(r0 + row) * D2P + n0 + col], lo);
                }
            }
            __syncthreads();
        }
        soft_sync(p.bar, ++bgen);

        // ---------- phase B: ht2 = 2*sig(xt2 @ R) * ht   (K=320pad, 16x32 tile)
        {
            const int ksb = (wid < 2) ? wid * 3 : 2 + wid * 2;   // {0,3,6,8}
            const int kse = (wid < 2) ? ksb + 3 : ksb + 2;       // {3,6,8,10}
            const int n0 = pair << 5;
            const __bf16* pah  = p.xt2h + (rbB + ln15) * D2P + kl;
            const __bf16* pal  = p.xt2l + (rbB + ln15) * D2P + kl;
            const __bf16* pbh0 = p.Rth + (n0 + ln15) * D2P + kl;
            const __bf16* pbl0 = p.Rtl + (n0 + ln15) * D2P + kl;
            const __bf16* pbh1 = p.Rth + (n0 + 16 + ln15) * D2P + kl;
            const __bf16* pbl1 = p.Rtl + (n0 + 16 + ln15) * D2P + kl;
            f32x4 acc0 = vz, acc20 = vz, acc1 = vz, acc21 = vz;
#pragma unroll
            for (int ks = ksb; ks < kse; ++ks) {
                const int ko = ks << 5;
                bf16x8 ah  = vload16(pah + ko);
                bf16x8 al  = vload16(pal + ko);
                bf16x8 bh0 = *(const bf16x8*)(pbh0 + ko);
                bf16x8 bl0 = *(const bf16x8*)(pbl0 + ko);
                bf16x8 bh1 = *(const bf16x8*)(pbh1 + ko);
                bf16x8 bl1 = *(const bf16x8*)(pbl1 + ko);
                acc0  = MFMA(ah, bh0, acc0);
                acc20 = MFMA(ah, bl0, acc20);
                acc20 = MFMA(al, bh0, acc20);
                acc1  = MFMA(ah, bh1, acc1);
                acc21 = MFMA(ah, bl1, acc21);
                acc21 = MFMA(al, bh1, acc21);
            }
            const f32x4 t0 = acc0 + acc20;
            const f32x4 t1 = acc1 + acc21;
#pragma unroll
            for (int j = 0; j < 4; ++j) {
                red[0][wid][(lane << 2) + j] = t0[j];
                red[1][wid][(lane << 2) + j] = t1[j];
            }
            __syncthreads();
            {
                const int row = tid >> 4, col = tid & 15;
                const int l4 = ((((row >> 2) << 4) | col) << 2) | (row & 3);
#pragma unroll
                for (int c = 0; c < 2; ++c) {
                    const float sm = red[c][0][l4] + red[c][1][l4] + red[c][2][l4] + red[c][3][l4];
                    const int n = n0 + (c << 4) + col;
                    const size_t idx = (size_t)(rbB + row) * HH + n;
                    const float vv = 2.0f * sigf(sm) * p.ht[idx];   // ht is WG-local
                    __bf16 hi, lo; bsplit(vv, &hi, &lo);
                    vstore_bf16(&p.ht2h[idx], hi);
                    vstore_bf16(&p.ht2l[idx], lo);
                }
            }
            __syncthreads();
        }
        soft_sync(p.bar, ++bgen);

        // ---------- phase C: gates = xt2@Wih + ht2@Whh + b; cell update (16x32)
        {
            const int h0 = pair << 5;
            const __bf16 *pah, *pal, *pwh, *pwl;
            int sA, ksb, kse;
            if (wid < 2) {
                sA = D2P;
                pah = p.xt2h; pal = p.xt2l; pwh = p.Wth; pwl = p.Wtl;
                ksb = wid * 5; kse = ksb + 5;
            } else {
                sA = HH;
                pah = p.ht2h; pal = p.ht2l; pwh = p.Hth; pwl = p.Htl;
                ksb = (wid - 2) * 8; kse = ksb + 8;
            }
            const __bf16* Ah  = pah + (rbB + ln15) * sA + kl;
            const __bf16* Al  = pal + (rbB + ln15) * sA + kl;
            const __bf16* Bh0 = pwh + (h0 + ln15) * sA + kl;
            const __bf16* Bl0 = pwl + (h0 + ln15) * sA + kl;
            const __bf16* Bh1 = pwh + (h0 + 16 + ln15) * sA + kl;
            const __bf16* Bl1 = pwl + (h0 + 16 + ln15) * sA + kl;
            const int segoff = HH * sA;
            f32x4 acc[8]  = {vz, vz, vz, vz, vz, vz, vz, vz};   // [seg*2 + colhalf]
            f32x4 acc2[8] = {vz, vz, vz, vz, vz, vz, vz, vz};
#pragma unroll 2
            for (int ks = ksb; ks < kse; ++ks) {
                const int ko = ks << 5;
                bf16x8 ah = vload16(Ah + ko);
                bf16x8 al = vload16(Al + ko);
#pragma unroll
                for (int s = 0; s < 4; ++s) {
                    bf16x8 wh0 = *(const bf16x8*)(Bh0 + s * segoff + ko);
                    bf16x8 wl0 = *(const bf16x8*)(Bl0 + s * segoff + ko);
                    bf16x8 wh1 = *(const bf16x8*)(Bh1 + s * segoff + ko);
                    bf16x8 wl1 = *(const bf16x8*)(Bl1 + s * segoff + ko);
                    acc[s * 2]      = MFMA(ah, wh0, acc[s * 2]);
                    acc2[s * 2]     = MFMA(ah, wl0, acc2[s * 2]);
                    acc2[s * 2]     = MFMA(al, wh0, acc2[s * 2]);
                    acc[s * 2 + 1]  = MFMA(ah, wh1, acc[s * 2 + 1]);
                    acc2[s * 2 + 1] = MFMA(ah, wl1, acc2[s * 2 + 1]);
                    acc2[s * 2 + 1] = MFMA(al, wh1, acc2[s * 2 + 1]);
                }
            }
#pragma unroll
            for (int q = 0; q < 8; ++q) {
                const f32x4 tot = acc[q] + acc2[q];
#pragma unroll
                for (int j = 0; j < 4; ++j) red[q][wid][(lane << 2) + j] = tot[j];
            }
            __syncthreads();
            {
                const int row = tid >> 4, hl = tid & 15;
                const int l4 = ((((row >> 2) << 4) | hl) << 2) | (row & 3);
#pragma unroll
                for (int c = 0; c < 2; ++c) {
                    const int h = h0 + (c << 4) + hl;
                    float g[4];
#pragma unroll
                    for (int s = 0; s < 4; ++s) {
                        const int q = s * 2 + c;
                        const int n = s * HH + h;
                        g[s] = red[q][0][l4] + red[q][1][l4] + red[q][2][l4] + red[q][3][l4]
                             + p.bih[n] + p.bhh[n];
                    }
                    const size_t idx = (size_t)(rbB + row) * HH + h;
                    const float cold = p.ct[idx];                  // ct is WG-local
                    const float cn = sigf(g[1]) * cold + sigf(g[0]) * tanhf(g[2]);
                    const float hn = sigf(g[3]) * tanhf(cn);
                    p.ct[idx] = cn;
                    p.ht[idx] = hn;                                // ht is WG-local
                    __bf16 hi, lo; bsplit(hn, &hi, &lo);
                    vstore_bf16(&p.hth[idx], hi);
                    vstore_bf16(&p.htl[idx], lo);
                    p.hseq[((size_t)(rbB + row) * SS + t) * HH + h] = __float2bfloat16(hn);
                }
            }
            __syncthreads();
        }
        soft_sync(p.bar, ++bgen);
    }
}

// ---------------------------------------------------------------------------
// Conv + relu + maxpool over time (unchanged; hseq is bf16 bit-identical).
// ---------------------------------------------------------------------------
__global__ __launch_bounds__(256) void conv_kernel(
    const __hip_bfloat16* __restrict__ hseq,
    const float* __restrict__ w3, const float* __restrict__ cb3,
    const float* __restrict__ w4, const float* __restrict__ cb4,
    const float* __restrict__ w5, const float* __restrict__ cb5,
    float* __restrict__ feats)
{
    __shared__ float sh[20 * 516];
    __shared__ float part[16 * 16 * 9];
    __shared__ int rmax[9];
    const int b = blockIdx.x;
    const int tid = threadIdx.x;
    if (tid < 9) rmax[tid] = 0;
    const int wv = tid >> 6, lane = tid & 63;
    const int t0l = lane >> 2, hs = lane & 3;

    for (int p = 0; p < 16; ++p) {
        __syncthreads();
#pragma unroll
        for (int i = 0; i < 5; ++i) {
            int e = tid + (i << 8);
            int row = e >> 6, q = e & 63;
            int tg = p * 16 + row;
            float v[8];
            if (tg < SS) {
                uint4 u = *(const uint4*)(hseq + (((size_t)b * SS + tg) << 9) + (q << 3));
                v[0] = __uint_as_float(u.x << 16); v[1] = __uint_as_float(u.x & 0xffff0000u);
                v[2] = __uint_as_float(u.y << 16); v[3] = __uint_as_float(u.y & 0xffff0000u);
                v[4] = __uint_as_float(u.z << 16); v[5] = __uint_as_float(u.z & 0xffff0000u);
                v[6] = __uint_as_float(u.w << 16); v[7] = __uint_as_float(u.w & 0xffff0000u);
            } else {
#pragma unroll
                for (int j = 0; j < 8; ++j) v[j] = 0.f;
            }
#pragma unroll
            for (int j = 0; j < 8; ++j) sh[row * 516 + q * 8 + j] = v[j];
        }
        __syncthreads();

        float acc[9];
#pragma unroll
        for (int j = 0; j < 9; ++j) acc[j] = 0.f;
        for (int k = 0; k < 32; ++k) {
            const int h = (wv << 7) + (k << 2) + hs;
            const float v0 = sh[(t0l + 0) * 516 + h];
            const float v1 = sh[(t0l + 1) * 516 + h];
            const float v2 = sh[(t0l + 2) * 516 + h];
            const float v3 = sh[(t0l + 3) * 516 + h];
            const float v4 = sh[(t0l + 4) * 516 + h];
#pragma unroll
            for (int f = 0; f < 3; ++f) {
                acc[f]     += v0 * w3[(f * 3 + 0) * 512 + h] + v1 * w3[(f * 3 + 1) * 512 + h]
                            + v2 * w3[(f * 3 + 2) * 512 + h];
                acc[3 + f] += v0 * w4[(f * 4 + 0) * 512 + h] + v1 * w4[(f * 4 + 1) * 512 + h]
                            + v2 * w4[(f * 4 + 2) * 512 + h] + v3 * w4[(f * 4 + 3) * 512 + h];
                acc[6 + f] += v0 * w5[(f * 5 + 0) * 512 + h] + v1 * w5[(f * 5 + 1) * 512 + h]
                            + v2 * w5[(f * 5 + 2) * 512 + h] + v3 * w5[(f * 5 + 3) * 512 + h]
                            + v4 * w5[(f * 5 + 4) * 512 + h];
            }
        }
        const int pi = (wv << 2) + hs;
#pragma unroll
        for (int j = 0; j < 9; ++j) part[(pi * 16 + t0l) * 9 + j] = acc[j];
        __syncthreads();
        if (tid < 144) {
            const int tl = tid / 9, j = tid % 9;
            float s = 0.f;
#pragma unroll
            for (int pp = 0; pp < 16; ++pp) s += part[(pp * 16 + tl) * 9 + j];
            const int fsz = j < 3 ? 3 : (j < 6 ? 4 : 5);
            const int t0 = p * 16 + tl;
            if (t0 <= SS - fsz) {
                const float bias = j < 3 ? cb3[j] : (j < 6 ? cb4[j - 3] : cb5[j - 6]);
                float v = s + bias;
                v = v > 0.f ? v : 0.f;
                atomicMax(&rmax[j], __float_as_int(v));
            }
        }
    }
    __syncthreads();
    if (tid < 9) feats[b * 9 + tid] = __int_as_float(rmax[tid]);
}

__global__ void final_kernel(const float* __restrict__ feats,
                             const float* __restrict__ lin_w,
                             const float* __restrict__ lin_b,
                             float* __restrict__ out)
{
    const int b = threadIdx.x;
    float o0 = lin_b[0], o1 = lin_b[1];
#pragma unroll
    for (int j = 0; j < 9; ++j) {
        const float f = feats[b * 9 + j];
        o0 += f * lin_w[j * 2 + 0];
        o1 += f * lin_w[j * 2 + 1];
    }
    out[b * 2 + 0] = o0;
    out[b * 2 + 1] = o1;
}

extern "C" void kernel_launch(void* const* d_in, const int* in_sizes, int n_in,
                              void* d_out, int out_size, void* d_ws, size_t ws_size,
                              hipStream_t stream) {
    const float* x    = (const float*)d_in[0];
    const float* W_in = (const float*)d_in[1];
    const float* b_in = (const float*)d_in[2];
    const float* Wih  = (const float*)d_in[3];
    const float* Whh  = (const float*)d_in[4];
    const float* bih  = (const float*)d_in[5];
    const float* bhh  = (const float*)d_in[6];
    const float* Q    = (const float*)d_in[7];
    const float* R    = (const float*)d_in[8];
    const float* lin_w = (const float*)d_in[9];
    const float* lin_b = (const float*)d_in[10];
    const float* w3 = (const float*)d_in[11];
    const float* cb3 = (const float*)d_in[12];
    const float* w4 = (const float*)d_in[13];
    const float* cb4 = (const float*)d_in[14];
    const float* w5 = (const float*)d_in[15];
    const float* cb5 = (const float*)d_in[16];

    char* base = (char*)d_ws;
    // --- zeroed region (barrier + recurrent state) ---
    unsigned* bar  = (unsigned*)base;                         // 4 KiB reserved
    float*  ht     = (float*)(base + 4096);                   // 256x512 f32
    float*  ct     = ht + (size_t)BB * HH;
    __bf16* hth    = (__bf16*)(ct + (size_t)BB * HH);         // 256x512 bf16
    __bf16* htl    = hth + (size_t)BB * HH;
    __bf16* ht2h   = htl + (size_t)BB * HH;
    __bf16* ht2l   = ht2h + (size_t)BB * HH;
    __bf16* xt2h   = ht2l + (size_t)BB * HH;                  // 256x320 bf16
    __bf16* xt2l   = xt2h + (size_t)BB * D2P;
    char*   zend   = (char*)(xt2l + (size_t)BB * D2P);
    const size_t zero_bytes = (size_t)(zend - base);          // ~2.4 MB
    // --- rest ---
    float*  xp     = (float*)zend;                            // 65536 x 300 f32
    __hip_bfloat16* hseq = (__hip_bfloat16*)(xp + (size_t)BB * SS * D2);
    float*  feats  = (float*)(hseq + (size_t)BB * SS * HH);
    __bf16* Qth    = (__bf16*)(feats + BB * 9);               // [304][512]
    __bf16* Qtl    = Qth + 304 * 512;
    __bf16* Rth    = Qtl + 304 * 512;                         // [512][320]
    __bf16* Rtl    = Rth + 512 * D2P;
    __bf16* Wth    = Rtl + 512 * D2P;                         // Wih^T [2048][320]
    __bf16* Wtl    = Wth + 2048 * D2P;
    __bf16* Hth    = Wtl + 2048 * D2P;                        // Whh^T [2048][512]
    __bf16* Htl    = Hth + (size_t)2048 * 512;

    hipMemsetAsync(base, 0, zero_bytes, stream);

    // xp = tanh(x @ W_in + b_in):  M=65536, K=300, N=300 (fp32)
    gemm_tile<<<dim3(5, 2048), 256, 0, stream>>>(x, DIN, W_in, D2, DIN, D2,
                                                 xp, D2, b_in, 0, 0);
    split_weights<<<dim3(1024), 256, 0, stream>>>(Q, R, Wih, Whh,
                                                  Qth, Qtl, Rth, Rtl,
                                                  Wth, Wtl, Hth, Htl);

    MogParams P;
    P.xp = xp; P.bih = bih; P.bhh = bhh;
    P.Qth = Qth; P.Qtl = Qtl; P.Rth = Rth; P.Rtl = Rtl;
    P.Wth = Wth; P.Wtl = Wtl; P.Hth = Hth; P.Htl = Htl;
    P.xt2h = xt2h; P.xt2l = xt2l; P.hth = hth; P.htl = htl;
    P.ht2h = ht2h; P.ht2l = ht2l;
    P.ht = ht; P.ct = ct; P.hseq = hseq; P.bar = bar;
    void* kargs[] = { &P };
    hipLaunchCooperativeKernel((const void*)mog_lstm, dim3(NWG), dim3(256),
                               kargs, 0, stream);

    conv_kernel<<<dim3(256), 256, 0, stream>>>(hseq, w3, cb3, w4, cb4, w5, cb5, feats);
    final_kernel<<<dim3(1), 256, 0, stream>>>(feats, lin_w, lin_b, (float*)d_out);
}